// Round 8
// baseline (380.067 us; speedup 1.0000x reference)
//
#include <hip/hip_runtime.h>
#include <math.h>

#define BATCH 256
#define NNODE 256
#define FIN   128
#define HID   48
#define DOUT  97

// packed transposed weight planes (ushort elements, per-plane offsets)
#define WOFF_DW0 0        // dW0^T [48][128]
#define WOFF_DW  6144     // dW[i]^T 4 x [48][64]
#define WOFF_UW  18432    // uW[i]^T 3 x [48][64]
#define WOFF_UWL 27648    // uWl^T  [112][64]
#define WTOT     34816    // per-plane stride

typedef __attribute__((ext_vector_type(8))) short bf16x8_t;
typedef __attribute__((ext_vector_type(4))) float f32x4_t;

__device__ inline unsigned short f2bf(float x) {
  unsigned u = __float_as_uint(x);
  u += 0x7fff + ((u >> 16) & 1);
  return (unsigned short)(u >> 16);
}
__device__ inline float bf2f(unsigned short h) {
  return __uint_as_float(((unsigned)h) << 16);
}

template<int L> __device__ inline float grp_sum(float v) {
  #pragma unroll
  for (int o = L >> 1; o > 0; o >>= 1) v += __shfl_xor(v, o);
  return v;
}
template<int L> __device__ inline int grp_isum(int v) {
  #pragma unroll
  for (int o = L >> 1; o > 0; o >>= 1) v += __shfl_xor(v, o);
  return v;
}

// ---------- transpose + 3-plane split ALL weights (runs once, tiny) ----------
__global__ __launch_bounds__(256) void k_splitW3(const float* __restrict__ dW0,
                                                 const float* __restrict__ dW,
                                                 const float* __restrict__ uW,
                                                 const float* __restrict__ uWl,
                                                 unsigned short* __restrict__ Wp) {
  int idx = blockIdx.x * 256 + threadIdx.x;
  if (idx >= WTOT) return;
  float v;
  if (idx < WOFF_DW) {                   // dW0^T [48][128]
    int f = idx / 128, kk = idx - f * 128;
    v = dW0[kk * HID + f];
  } else if (idx < WOFF_UW) {            // dW[i]^T [48][64]
    int r = idx - WOFF_DW;
    int i = r / 3072; r -= i * 3072;
    int f = r / 64, kk = r - f * 64;
    v = (kk < HID) ? dW[((size_t)i * HID + kk) * HID + f] : 0.f;
  } else if (idx < WOFF_UWL) {           // uW[i]^T [48][64]
    int r = idx - WOFF_UW;
    int i = r / 3072; r -= i * 3072;
    int f = r / 64, kk = r - f * 64;
    v = (kk < HID) ? uW[((size_t)i * HID + kk) * HID + f] : 0.f;
  } else {                               // uWl^T [112][64]
    int r = idx - WOFF_UWL;
    int f = r / 64, kk = r - f * 64;
    v = (f < DOUT && kk < HID) ? uWl[(size_t)kk * DOUT + f] : 0.f;
  }
  unsigned short h = f2bf(v);
  float r1 = v - bf2f(h);
  unsigned short m = f2bf(r1);
  float r2 = r1 - bf2f(m);
  unsigned short l = f2bf(r2);
  Wp[idx] = h;
  Wp[idx + WTOT] = m;
  Wp[idx + 2 * WTOT] = l;
}

// ---------- GCN@128 phase (1024 threads): 24 (m,ft) tasks per step ----------
template<int MODE>   // 0 -> write H1; 1 -> scatter-add into H0b via sPerm1
__device__ inline void gcn128_phase(const float* __restrict__ Xg,
                                    const unsigned short* __restrict__ Wpl,
                                    const unsigned short* __restrict__ A1,
                                    const float* __restrict__ D1b,
                                    const float* __restrict__ bias,
                                    char* yt0, char* yt1,
                                    float* __restrict__ H1,
                                    float* __restrict__ H0b,
                                    const int* sPerm1, int t) {
  int w = t >> 6, lane = t & 63;
  int r = lane & 15, q = lane >> 4;
  // step A: XWdT hi/lo into LDS [48][128] swizzled; tasks (m 0..7) x (ft 0..2)
  for (int task = w; task < 24; task += 16) {
    int m = task / 3, ft = task - m * 3;
    const float* xr = Xg + (size_t)(m * 16 + r) * 48;
    bf16x8_t ah[2], am[2], al[2];
    #pragma unroll
    for (int ks = 0; ks < 2; ks++) {
      int col0 = ks * 32 + q * 8;
      float v[8];
      if (col0 + 8 <= 48) {
        float4 a4 = *(const float4*)(xr + col0);
        float4 b4 = *(const float4*)(xr + col0 + 4);
        v[0]=a4.x; v[1]=a4.y; v[2]=a4.z; v[3]=a4.w;
        v[4]=b4.x; v[5]=b4.y; v[6]=b4.z; v[7]=b4.w;
      } else {
        #pragma unroll
        for (int j = 0; j < 8; j++) v[j] = (col0 + j < 48) ? xr[col0 + j] : 0.f;
      }
      #pragma unroll
      for (int j = 0; j < 8; j++) {
        unsigned short h = f2bf(v[j]); float r1 = v[j] - bf2f(h);
        unsigned short mm = f2bf(r1);  float r2 = r1 - bf2f(mm);
        ah[ks][j] = (short)h; am[ks][j] = (short)mm; al[ks][j] = (short)f2bf(r2);
      }
    }
    int row0 = m * 16 + q * 4;
    float4 dv4 = *(const float4*)(D1b + row0);
    float dvv[4] = {dv4.x, dv4.y, dv4.z, dv4.w};
    int fl = ft * 16 + r;
    const unsigned short* wb = Wpl + (size_t)fl * 64 + q * 8;
    f32x4_t acc = {0.f, 0.f, 0.f, 0.f};
    #pragma unroll
    for (int ks = 0; ks < 2; ks++) {
      bf16x8_t bh = *(const bf16x8_t*)(wb + ks * 32);
      bf16x8_t bm = *(const bf16x8_t*)(wb + WTOT + ks * 32);
      bf16x8_t bl = *(const bf16x8_t*)(wb + 2 * WTOT + ks * 32);
      acc = __builtin_amdgcn_mfma_f32_16x16x32_bf16(ah[ks], bh, acc, 0, 0, 0);
      acc = __builtin_amdgcn_mfma_f32_16x16x32_bf16(ah[ks], bm, acc, 0, 0, 0);
      acc = __builtin_amdgcn_mfma_f32_16x16x32_bf16(am[ks], bh, acc, 0, 0, 0);
      acc = __builtin_amdgcn_mfma_f32_16x16x32_bf16(am[ks], bm, acc, 0, 0, 0);
      acc = __builtin_amdgcn_mfma_f32_16x16x32_bf16(ah[ks], bl, acc, 0, 0, 0);
      acc = __builtin_amdgcn_mfma_f32_16x16x32_bf16(al[ks], bh, acc, 0, 0, 0);
    }
    #pragma unroll
    for (int reg = 0; reg < 4; reg++) {
      float vv = dvv[reg] * acc[reg];
      unsigned short hi = f2bf(vv);
      unsigned short lo = f2bf(vv - bf2f(hi));
      int byte = (fl * 256 + (row0 + reg) * 2) ^ ((fl & 7) << 4);
      *(unsigned short*)(yt0 + byte) = hi;
      *(unsigned short*)(yt1 + byte) = lo;
    }
  }
  __syncthreads();
  // step B: tasks (it 0..7) x (ft 0..2)
  for (int task = w; task < 24; task += 16) {
    int it = task / 3, ft = task - it * 3;
    const unsigned short* ap = A1 + (size_t)(it * 16 + r) * 128 + q * 8;
    bf16x8_t af[4];
    #pragma unroll
    for (int ks = 0; ks < 4; ks++) af[ks] = *(const bf16x8_t*)(ap + ks * 32);
    int fl = ft * 16 + r;
    f32x4_t acc = {0.f, 0.f, 0.f, 0.f};
    #pragma unroll
    for (int ks = 0; ks < 4; ks++) {
      int byte = (fl * 256 + (ks * 32 + q * 8) * 2) ^ ((fl & 7) << 4);
      bf16x8_t bh = *(const bf16x8_t*)(yt0 + byte);
      bf16x8_t bl = *(const bf16x8_t*)(yt1 + byte);
      acc = __builtin_amdgcn_mfma_f32_16x16x32_bf16(af[ks], bh, acc, 0, 0, 0);
      acc = __builtin_amdgcn_mfma_f32_16x16x32_bf16(af[ks], bl, acc, 0, 0, 0);
    }
    float bfv = bias[fl];
    #pragma unroll
    for (int reg = 0; reg < 4; reg++) {
      int rr = it * 16 + q * 4 + reg;
      int sbyte = (fl * 256 + rr * 2) ^ ((fl & 7) << 4);
      float selfv = bf2f(*(const unsigned short*)(yt0 + sbyte))
                  + bf2f(*(const unsigned short*)(yt1 + sbyte));
      float d = D1b[rr];
      float v = d * acc[reg] + 2.f * d * selfv + bfv;
      v = fmaxf(v, 0.f);
      if (MODE == 0) H1[(size_t)rr * 48 + fl] = v;
      else {
        int node = sPerm1[rr];
        H0b[(size_t)node * 48 + fl] += v;
      }
    }
  }
  __syncthreads();
}

// ---------- inner-U device helpers (1024-thread) ----------
__device__ inline void xw_dphase(const float* hin, const float* W, const float* dv,
                                 float* xwd, int n, int t) {
  for (int idx = t; idx < n * 48; idx += 1024) {
    int j = idx / 48, f = idx - j * 48;
    const float* hr = hin + j * 48;
    float a = 0.f;
    #pragma unroll
    for (int g = 0; g < 48; g++) a += hr[g] * W[g * 48 + f];
    xwd[idx] = dv[j] * a;
  }
}

__device__ inline void anxw_phase(const float* A, int lda, const float* xwd,
                                  const float* dv, const float* bias,
                                  float* hout, int n, int t) {
  for (int idx = t; idx < n * 48; idx += 1024) {
    int i = idx / 48, f = idx - i * 48;
    const float* ar = A + i * lda;
    float acc = 0.f;
    #pragma unroll 4
    for (int j = 0; j < n; j++) acc += ar[j] * xwd[j * 48 + f];
    float di = dv[i];
    float v = di * acc + 2.f * di * xwd[i * 48 + f] + bias[f];
    hout[idx] = fmaxf(v, 0.f);
  }
}

// pool + aug fused: score, rank, {gather || aug-dot}, dinv
template<int N, int K>
__device__ inline void pool_aug_phaseT(const float* h, const float* p,
                                       const float* A, int lda,
                                       float* Ao, int ldo,
                                       float* sS, int* perm, float* hin,
                                       float* dout, int t) {
  constexpr int LPR = 1024 / N;
  int row = t / LPR, sub = t % LPR;
  float pn = 0.f;
  #pragma unroll
  for (int g = 0; g < 48; g++) pn += p[g] * p[g];
  const float* hr = h + row * 48;
  float acc = 0.f;
  for (int g = sub; g < 48; g += LPR) acc += hr[g] * p[g];
  acc = grp_sum<LPR>(acc);
  if (sub == 0) sS[row] = tanhf(acc / sqrtf(pn));
  __syncthreads();
  {
    float v = sS[row];
    int rk = 0;
    for (int j = sub; j < N; j += LPR) {
      float u = sS[j];
      rk += (u > v) || (u == v && j < row);
    }
    rk = grp_isum<LPR>(rk);
    if (sub == 0 && rk < K) perm[rk] = row;
  }
  __syncthreads();
  for (int idx = t; idx < K * 48; idx += 1024) {
    int r = idx / 48, g = idx - r * 48;
    int pi = perm[r];
    hin[idx] = h[pi * 48 + g] * sS[pi];
  }
  for (int idx = t; idx < K * K; idx += 1024) {
    int r = idx / K, c = idx - r * K;
    int pr = perm[r], pc = perm[c];
    const float* ra = A + pr * lda;
    const float* rc = A + pc * lda;
    float a2 = 0.f;
    #pragma unroll 4
    for (int j = 0; j < N; j++) a2 += ra[j] * rc[j];
    float v = a2 + 2.f * ra[pc];
    Ao[r * ldo + c] = (r == c) ? 0.f : v;
  }
  __syncthreads();
  {
    constexpr int LPR2 = 1024 / K;
    constexpr int LG = (LPR2 > 64 ? 64 : LPR2);
    int row2 = t / LPR2, sub2 = t % LPR2;
    float s = 0.f;
    for (int j = sub2; j < K; j += LPR2) s += Ao[row2 * ldo + j];
    s = grp_sum<LG>(s);
    if (sub2 == 0) dout[row2] = 1.0f / sqrtf(s + 2.0f);
  }
  __syncthreads();
}

__device__ inline void scat_phase(const int* perm, const float* src, float* dst,
                                  int k, int t) {
  for (int idx = t; idx < k * 48; idx += 1024) {
    int r = idx / 48, g = idx - r * 48;
    dst[perm[r] * 48 + g] += src[idx];
  }
  __syncthreads();
}

// ========== k_gunet: the ENTIRE network, one block per batch ==========
__global__ __launch_bounds__(1024) void k_gunet(
    const float* __restrict__ x, const float* __restrict__ A0,
    const unsigned short* __restrict__ Wp,
    const float* __restrict__ db0, const float* __restrict__ dW,
    const float* __restrict__ dbv, const float* __restrict__ pp,
    const float* __restrict__ uW, const float* __restrict__ ub,
    const float* __restrict__ ubl,
    const float* __restrict__ c1W, const float* __restrict__ c1b,
    const float* __restrict__ c2W, const float* __restrict__ c2b,
    const float* __restrict__ oW, const float* __restrict__ ob,
    unsigned short* __restrict__ Abf0g, unsigned short* __restrict__ Abf1g,
    float* __restrict__ H0g, float* __restrict__ H1g, float* __restrict__ D1g,
    float* __restrict__ out) {
  int b = blockIdx.x, t = threadIdx.x;
  __shared__ __align__(16) char arena[63488];
  __shared__ int sPerm1[128];
  __shared__ __align__(16) float sD0[256];

  const float* A0b = A0 + (size_t)b * 65536;
  unsigned short* Ab = Abf0g + (size_t)b * 65536;
  float* H0b = H0g + (size_t)b * 256 * 48;
  float* H1 = H1g + (size_t)b * 128 * 48;
  unsigned short* A1 = Abf1g + (size_t)b * 128 * 128;
  float* D1b = D1g + (size_t)b * 128;
  int w = t >> 6, lane = t & 63;
  int r = lane & 15, q = lane >> 4;

  // ===== P0+P1A (merged): wave w converts its OWN 16 A0-rows (d in regs, no
  // barrier to stepA), then first-GCN stepA (XWdT into LDS). One barrier saved;
  // A0 (67MB) and x (33MB) streaming reads share one issue window. =====
  float dvv0[4];
  {
    #pragma unroll
    for (int i = 0; i < 16; i++) {
      int row = w * 16 + i;
      const float4* rp = (const float4*)(A0b + (size_t)row * 256);
      float4 v = rp[lane];
      unsigned long long pk = (unsigned long long)f2bf(v.x)
                            | ((unsigned long long)f2bf(v.y) << 16)
                            | ((unsigned long long)f2bf(v.z) << 32)
                            | ((unsigned long long)f2bf(v.w) << 48);
      *(unsigned long long*)(Ab + (size_t)row * 256 + lane * 4) = pk;
      float s = v.x + v.y + v.z + v.w;
      s = grp_sum<64>(s);
      float dval = 1.0f / sqrtf(s + 2.0f);
      if (lane == 0) sD0[row] = dval;
      if (q == (i >> 2)) dvv0[i & 3] = dval;   // compile-time index (rule #20)
    }
  }
  {
    char* yt0 = arena;            // XWdT hi [48][256] bf16, swizzled (24576 B)
    char* yt1 = arena + 24576;    // XWdT lo
    const float* Xb = x + (size_t)b * 256 * 128;
    // step A: m = w (16 tiles); dvv0 = own-row d values (intra-wave dep only)
    {
      int m = w;
      const float* xr = Xb + (size_t)(m * 16 + r) * 128;
      bf16x8_t ah[4], am[4], al[4];
      #pragma unroll
      for (int ks = 0; ks < 4; ks++) {
        int col0 = ks * 32 + q * 8;
        float4 a4 = *(const float4*)(xr + col0);
        float4 b4 = *(const float4*)(xr + col0 + 4);
        float v[8] = {a4.x, a4.y, a4.z, a4.w, b4.x, b4.y, b4.z, b4.w};
        #pragma unroll
        for (int j = 0; j < 8; j++) {
          unsigned short h = f2bf(v[j]); float r1 = v[j] - bf2f(h);
          unsigned short mm = f2bf(r1);  float r2 = r1 - bf2f(mm);
          ah[ks][j] = (short)h; am[ks][j] = (short)mm; al[ks][j] = (short)f2bf(r2);
        }
      }
      int row0 = m * 16 + q * 4;
      #pragma unroll
      for (int ft = 0; ft < 3; ft++) {
        int fl = ft * 16 + r;
        const unsigned short* wb = Wp + WOFF_DW0 + (size_t)fl * 128 + q * 8;
        f32x4_t acc = {0.f, 0.f, 0.f, 0.f};
        #pragma unroll
        for (int ks = 0; ks < 4; ks++) {
          bf16x8_t bh = *(const bf16x8_t*)(wb + ks * 32);
          bf16x8_t bm = *(const bf16x8_t*)(wb + WTOT + ks * 32);
          bf16x8_t bl = *(const bf16x8_t*)(wb + 2 * WTOT + ks * 32);
          acc = __builtin_amdgcn_mfma_f32_16x16x32_bf16(ah[ks], bh, acc, 0, 0, 0);
          acc = __builtin_amdgcn_mfma_f32_16x16x32_bf16(ah[ks], bm, acc, 0, 0, 0);
          acc = __builtin_amdgcn_mfma_f32_16x16x32_bf16(am[ks], bh, acc, 0, 0, 0);
          acc = __builtin_amdgcn_mfma_f32_16x16x32_bf16(am[ks], bm, acc, 0, 0, 0);
          acc = __builtin_amdgcn_mfma_f32_16x16x32_bf16(ah[ks], bl, acc, 0, 0, 0);
          acc = __builtin_amdgcn_mfma_f32_16x16x32_bf16(al[ks], bh, acc, 0, 0, 0);
        }
        #pragma unroll
        for (int reg = 0; reg < 4; reg++) {
          float vv = dvv0[reg] * acc[reg];
          unsigned short hi = f2bf(vv);
          unsigned short lo = f2bf(vv - bf2f(hi));
          int byte = (fl * 512 + (row0 + reg) * 2) ^ ((fl & 7) << 4);
          *(unsigned short*)(yt0 + byte) = hi;
          *(unsigned short*)(yt1 + byte) = lo;
        }
      }
    }
    __syncthreads();
    // step B: it = w
    {
      int it = w;
      const unsigned short* ap = Ab + (size_t)(it * 16 + r) * 256 + q * 8;
      bf16x8_t af[8];
      #pragma unroll
      for (int ks = 0; ks < 8; ks++) af[ks] = *(const bf16x8_t*)(ap + ks * 32);
      #pragma unroll
      for (int ft = 0; ft < 3; ft++) {
        int fl = ft * 16 + r;
        f32x4_t acc = {0.f, 0.f, 0.f, 0.f};
        #pragma unroll
        for (int ks = 0; ks < 8; ks++) {
          int byte = (fl * 512 + (ks * 32 + q * 8) * 2) ^ ((fl & 7) << 4);
          bf16x8_t bh = *(const bf16x8_t*)(yt0 + byte);
          bf16x8_t bl = *(const bf16x8_t*)(yt1 + byte);
          acc = __builtin_amdgcn_mfma_f32_16x16x32_bf16(af[ks], bh, acc, 0, 0, 0);
          acc = __builtin_amdgcn_mfma_f32_16x16x32_bf16(af[ks], bl, acc, 0, 0, 0);
        }
        float bfv = db0[fl];
        #pragma unroll
        for (int reg = 0; reg < 4; reg++) {
          int rr = it * 16 + q * 4 + reg;
          int sbyte = (fl * 512 + rr * 2) ^ ((fl & 7) << 4);
          float selfv = bf2f(*(const unsigned short*)(yt0 + sbyte))
                      + bf2f(*(const unsigned short*)(yt1 + sbyte));
          float d = sD0[rr];
          float v = d * acc[reg] + 2.f * d * selfv + bfv;
          H0b[(size_t)rr * 48 + fl] = fmaxf(v, 0.f);
        }
      }
    }
  }
  __syncthreads();

  // ===== P2: pool0 scores + rank (n=256 -> k=128) =====
  {
    float* sc = (float*)arena;    // [256]
    const float* p = pp;
    float pn = 0.f;
    #pragma unroll
    for (int g = 0; g < 48; g++) pn += p[g] * p[g];
    int row = t >> 2, sub = t & 3;
    const float* hr = H0b + (size_t)row * 48;
    float a = 0.f;
    for (int g = sub; g < 48; g += 4) a += hr[g] * p[g];
    a = grp_sum<4>(a);
    if (!sub) sc[row] = tanhf(a / sqrtf(pn));
    __syncthreads();
    float vv = sc[row];
    int rk = 0;
    for (int j = sub; j < 256; j += 4) {
      float u = sc[j];
      rk += (u > vv) || (u == vv && j < row);
    }
    rk = grp_isum<4>(rk);
    if (!sub && rk < 128) sPerm1[rk] = row;
  }
  __syncthreads();

  // ===== P3: gather into H1 (memory) || aug1 MFMA (A1 = (A0+I)^2 off-diag, exact) =====
  {
    float* sc = (float*)arena;
    for (int idx = t; idx < 128 * 48; idx += 1024) {
      int rr = idx / 48, g = idx - rr * 48;
      int pi = sPerm1[rr];
      H1[idx] = H0b[(size_t)pi * 48 + g] * sc[pi];
    }
    int it = w >> 1, fh = w & 1;
    int rowA = sPerm1[it * 16 + r];
    const unsigned short* pa = Ab + (size_t)rowA * 256 + q * 8;
    bf16x8_t af[8];
    #pragma unroll
    for (int ks = 0; ks < 8; ks++) {
      bf16x8_t a = *(const bf16x8_t*)(pa + ks * 32);
      int da = rowA - ks * 32 - q * 8;
      #pragma unroll
      for (int e = 0; e < 8; e++) if (da == e) a[e] = (short)0x3F80;
      af[ks] = a;
    }
    for (int ft = fh * 4; ft < fh * 4 + 4; ft++) {
      int rowB = sPerm1[ft * 16 + r];
      const unsigned short* pb = Ab + (size_t)rowB * 256 + q * 8;
      f32x4_t acc = {0.f, 0.f, 0.f, 0.f};
      #pragma unroll
      for (int ks = 0; ks < 8; ks++) {
        bf16x8_t bv = *(const bf16x8_t*)(pb + ks * 32);
        int db_ = rowB - ks * 32 - q * 8;
        #pragma unroll
        for (int e = 0; e < 8; e++) if (db_ == e) bv[e] = (short)0x3F80;
        acc = __builtin_amdgcn_mfma_f32_16x16x32_bf16(af[ks], bv, acc, 0, 0, 0);
      }
      int c = ft * 16 + r;
      #pragma unroll
      for (int reg = 0; reg < 4; reg++) {
        int rr = it * 16 + q * 4 + reg;
        float v = (rr == c) ? 0.f : acc[reg];
        A1[(size_t)rr * 128 + c] = f2bf(v);
      }
    }
  }
  __syncthreads();
  // D1 rowsum from bf16 A1 (exact); 8 lanes/row
  {
    int row = t >> 3, sub = t & 7;
    const unsigned* ar = (const unsigned*)(A1 + (size_t)row * 128);
    float s = 0.f;
    for (int jj = sub; jj < 64; jj += 8) {
      unsigned u = ar[jj];
      s += bf2f((unsigned short)(u & 0xffffu)) + bf2f((unsigned short)(u >> 16));
    }
    s = grp_sum<8>(s);
    if (sub == 0) D1b[row] = 1.0f / sqrtf(s + 2.0f);
  }
  __syncthreads();

  // ===== P4: encoder GCN@128 (dW[0], db[0]) -> H1 =====
  gcn128_phase<0>(H1, Wp + WOFF_DW, A1, D1b, dbv,
                  arena, arena + 12288, H1, nullptr, sPerm1, t);

  // ===== P5: inner U (enc lvl1..3 + dec j=3..2 + scatter into H1) =====
  {
    float* sS  = (float*)(arena);           // [128]
    int*   sP2 = (int*)(arena + 512);       // [64]
    int*   sP3 = (int*)(arena + 768);       // [32]
    int*   sP4 = (int*)(arena + 896);       // [16]
    float* sD2 = (float*)(arena + 960);     // [64]
    float* sD3 = (float*)(arena + 1216);    // [32]
    float* sD4 = (float*)(arena + 1344);    // [16]
    float* sA2 = (float*)(arena + 1536);    // [64][65]  -> 18176
    float* sA3 = (float*)(arena + 18176);   // [32][33]  -> 22400
    float* sH2 = (float*)(arena + 22400);   // [64][48]  -> 34688
    float* sH3 = (float*)(arena + 34688);   // [32][48]  -> 40832
    float* sXW = (float*)(arena + 40832);   // [64][48]  -> 53120
    float* hin = (float*)(arena + 53120);   // [32][48]  -> 59264
    float* sH4 = (float*)(arena + 59264);   // [16][48]  -> 62336
    float* sA4 = (float*)(arena + 62336);   // [16][17]  -> 63424

    // lvl1 pool scores + rank over H1 (n=128 -> k=64), LPR=8
    {
      const float* p = pp + 48;
      float pn = 0.f;
      #pragma unroll
      for (int g = 0; g < 48; g++) pn += p[g] * p[g];
      int row = t >> 3, sub = t & 7;
      const float* hr = H1 + (size_t)row * 48;
      float acc = 0.f;
      for (int g = sub; g < 48; g += 8) acc += hr[g] * p[g];
      acc = grp_sum<8>(acc);
      if (sub == 0) sS[row] = tanhf(acc / sqrtf(pn));
      __syncthreads();
      float v = sS[row];
      int rk = 0;
      for (int j = sub; j < 128; j += 8) {
        float u = sS[j];
        rk += (u > v) || (u == v && j < row);
      }
      rk = grp_isum<8>(rk);
      if (sub == 0 && rk < 64) sP2[rk] = row;
      __syncthreads();
    }
    // aug: A2 = (A1+I)^2 off-diag via MFMA from global A1 (exact); 1 tile/wave
    {
      int it = w >> 2, ft = w & 3;
      int rowA = sP2[it * 16 + r];
      int rowB = sP2[ft * 16 + r];
      const unsigned short* pa = A1 + (size_t)rowA * 128 + q * 8;
      const unsigned short* pb = A1 + (size_t)rowB * 128 + q * 8;
      f32x4_t acc = {0.f, 0.f, 0.f, 0.f};
      #pragma unroll
      for (int k0 = 0; k0 < 128; k0 += 32) {
        bf16x8_t a  = *(const bf16x8_t*)(pa + k0);
        bf16x8_t bv = *(const bf16x8_t*)(pb + k0);
        int daA = rowA - k0 - q * 8;
        int daB = rowB - k0 - q * 8;
        #pragma unroll
        for (int e = 0; e < 8; e++) {
          if (daA == e) a[e] = (short)0x3F80;
          if (daB == e) bv[e] = (short)0x3F80;
        }
        acc = __builtin_amdgcn_mfma_f32_16x16x32_bf16(a, bv, acc, 0, 0, 0);
      }
      int c = ft * 16 + r;
      #pragma unroll
      for (int reg = 0; reg < 4; reg++) {
        int rr = it * 16 + q * 4 + reg;
        sA2[rr * 65 + c] = (rr == c) ? 0.f : acc[reg];
      }
    }
    __syncthreads();
    // D2 rowsum (LPR=16)
    {
      int row = t >> 4, sub = t & 15;
      float s = 0.f;
      for (int j = sub; j < 64; j += 16) s += sA2[row * 65 + j];
      s = grp_sum<16>(s);
      if (sub == 0) sD2[row] = 1.0f / sqrtf(s + 2.0f);
    }
    __syncthreads();
    // lvl1 XWd: gather-fold from H1 global
    for (int idx = t; idx < 64 * 48; idx += 1024) {
      int j = idx / 48, f = idx - j * 48;
      int pi = sP2[j];
      const float* hr = H1 + (size_t)pi * 48;
      const float* W = dW + 2304;
      float a = 0.f;
      #pragma unroll
      for (int g = 0; g < 48; g++) a += hr[g] * W[g * 48 + f];
      sXW[idx] = sD2[j] * sS[pi] * a;
    }
    __syncthreads();
    anxw_phase(sA2, 65, sXW, sD2, dbv + 48, sH2, 64, t);
    __syncthreads();

    // lvl2 (64 -> 32)
    pool_aug_phaseT<64, 32>(sH2, pp + 96, sA2, 65, sA3, 33, sS, sP3, hin, sD3, t);
    xw_dphase(hin, dW + 2 * 2304, sD3, sXW, 32, t);
    __syncthreads();
    anxw_phase(sA3, 33, sXW, sD3, dbv + 96, sH3, 32, t);
    __syncthreads();

    // lvl3 (32 -> 16)
    pool_aug_phaseT<32, 16>(sH3, pp + 144, sA3, 33, sA4, 17, sS, sP4, hin, sD4, t);
    xw_dphase(hin, dW + 3 * 2304, sD4, sXW, 16, t);
    __syncthreads();
    anxw_phase(sA4, 17, sXW, sD4, dbv + 144, sH4, 16, t);
    __syncthreads();

    // dec j=3
    scat_phase(sP4, sH4, sH3, 16, t);
    xw_dphase(sH3, uW, sD3, sXW, 32, t);
    __syncthreads();
    anxw_phase(sA3, 33, sXW, sD3, ub, sH3, 32, t);
    __syncthreads();

    // dec j=2
    scat_phase(sP3, sH3, sH2, 32, t);
    xw_dphase(sH2, uW + 2304, sD2, sXW, 64, t);
    __syncthreads();
    anxw_phase(sA2, 65, sXW, sD2, ub + 48, sH2, 64, t);
    __syncthreads();

    // H1 += up(sH2)
    for (int idx = t; idx < 64 * 48; idx += 1024) {
      int r2 = idx / 48, g = idx - r2 * 48;
      H1[(size_t)sP2[r2] * 48 + g] += sH2[idx];
    }
  }
  __syncthreads();

  // ===== P6: decoder GCN@128 (uW[2], ub[2]) -> scatter-add into H0 =====
  gcn128_phase<1>(H1, Wp + WOFF_UW + 2 * 3072, A1, D1b, ub + 96,
                  arena, arena + 12288, nullptr, H0b, sPerm1, t);

  // ===== P7: final GCN (uWl): double-buffered fp32 yd tiles, LDS-staged A rows,
  // stepB(prev) || stepA(next) overlap (VALU/LDS vs MFMA/global) =====
  float* spl = (float*)(arena + 32896);       // sp [30][97] fp32, survives to P8
  {
    float* ydA = (float*)arena;               // [16][257] (16448 B)
    float* ydB = (float*)(arena + 16448);     // [16][257]
    unsigned* sAr = (unsigned*)(arena + 44536); // 30 rows x 133 unsigneds (15960 B)
    float* scp = (float*)(arena + 60496);     // [256]
    int* sord  = (int*)(arena + 61520);       // [32]

    bf16x8_t ah[2], am[2], al[2];
    {
      const float* xr = H0b + (size_t)(w * 16 + r) * 48;
      #pragma unroll
      for (int ks = 0; ks < 2; ks++) {
        int col0 = ks * 32 + q * 8;
        float v[8];
        if (col0 + 8 <= 48) {
          float4 a4 = *(const float4*)(xr + col0);
          float4 b4 = *(const float4*)(xr + col0 + 4);
          v[0]=a4.x; v[1]=a4.y; v[2]=a4.z; v[3]=a4.w;
          v[4]=b4.x; v[5]=b4.y; v[6]=b4.z; v[7]=b4.w;
        } else {
          #pragma unroll
          for (int j = 0; j < 8; j++) v[j] = (col0 + j < 48) ? xr[col0 + j] : 0.f;
        }
        #pragma unroll
        for (int j = 0; j < 8; j++) {
          unsigned short h = f2bf(v[j]); float r1 = v[j] - bf2f(h);
          unsigned short mm = f2bf(r1);  float r2 = r1 - bf2f(mm);
          ah[ks][j] = (short)h; am[ks][j] = (short)mm; al[ks][j] = (short)f2bf(r2);
        }
      }
    }
    int row0 = w * 16 + q * 4;
    float4 dv4 = *(const float4*)(sD0 + row0);
    float dvv[4] = {dv4.x, dv4.y, dv4.z, dv4.w};

    auto stepA = [&](int ft, float* ydt) {
      int fl = ft * 16 + r;
      const unsigned short* wb = Wp + WOFF_UWL + (size_t)fl * 64 + q * 8;
      f32x4_t acc = {0.f, 0.f, 0.f, 0.f};
      #pragma unroll
      for (int ks = 0; ks < 2; ks++) {
        bf16x8_t bh = *(const bf16x8_t*)(wb + ks * 32);
        bf16x8_t bm = *(const bf16x8_t*)(wb + WTOT + ks * 32);
        bf16x8_t bl = *(const bf16x8_t*)(wb + 2 * WTOT + ks * 32);
        acc = __builtin_amdgcn_mfma_f32_16x16x32_bf16(ah[ks], bh, acc, 0, 0, 0);
        acc = __builtin_amdgcn_mfma_f32_16x16x32_bf16(ah[ks], bm, acc, 0, 0, 0);
        acc = __builtin_amdgcn_mfma_f32_16x16x32_bf16(am[ks], bh, acc, 0, 0, 0);
        acc = __builtin_amdgcn_mfma_f32_16x16x32_bf16(am[ks], bm, acc, 0, 0, 0);
        acc = __builtin_amdgcn_mfma_f32_16x16x32_bf16(ah[ks], bl, acc, 0, 0, 0);
        acc = __builtin_amdgcn_mfma_f32_16x16x32_bf16(al[ks], bh, acc, 0, 0, 0);
      }
      #pragma unroll
      for (int reg = 0; reg < 4; reg++)
        ydt[r * 257 + row0 + reg] = dvv[reg] * acc[reg];
    };

    auto stepB = [&](int ft, int nf, const float* ydt) {
      int o = t >> 1, sub = t & 1;
      if (o < 30 * nf) {
        int rr = o / nf, f = o - rr * nf;
        int fl = ft * 16 + f;
        int node = sord[rr];
        const unsigned* ar = sAr + rr * 133 + sub * 64;
        const float* yp = &ydt[f * 257 + sub * 128];
        float s = 0.f;
        #pragma unroll 4
        for (int j = 0; j < 64; j++) {
          unsigned u = ar[j];
          s += bf2f((unsigned short)(u & 0xffffu)) * yp[2 * j]
             + bf2f((unsigned short)(u >> 16)) * yp[2 * j + 1];
        }
        s += __shfl_xor(s, 1);
        if (!sub) {
          float d = sD0[node];
          spl[rr * DOUT + fl] = d * s + 2.f * d * ydt[f * 257 + node] + ubl[fl];
        }
      }
    };

    stepA(6, ydA);               // tile holding f=96 (ranking column)
    __syncthreads();
    {                            // col-96 scores: 4 lanes per node (global A rows)
      int i = t >> 2, sub = t & 3;
      const unsigned short* ar = Ab + (size_t)i * 256 + sub * 64;
      const float* yp = &ydA[0 * 257 + sub * 64];
      float s = 0.f;
      for (int j = 0; j < 64; j += 2) {
        unsigned u = *(const unsigned*)(ar + j);
        s += bf2f((unsigned short)(u & 0xffffu)) * yp[j]
           + bf2f((unsigned short)(u >> 16)) * yp[j + 1];
      }
      s = grp_sum<4>(s);
      if (!sub) {
        float d = sD0[i];
        scp[i] = d * s + 2.f * d * ydA[0 * 257 + i];
      }
    }
    __syncthreads();
    {                            // exact top-30 rank
      int i = t >> 2, sub = t & 3;
      float v = scp[i];
      int rk = 0;
      int j0 = sub * 64;
      for (int j = j0; j < j0 + 64; j++) {
        float u = scp[j];
        rk += (u > v) || (u == v && j < i);
      }
      rk = grp_isum<4>(rk);
      if (!sub && rk < 30) sord[rk] = i;
    }
    __syncthreads();
    // stage the 30 selected A rows into LDS (read 97x by stepB instead of global)
    for (int idx = t; idx < 30 * 128; idx += 1024) {
      int rr = idx >> 7, cc = idx & 127;
      sAr[rr * 133 + cc] = ((const unsigned*)(Ab + (size_t)sord[rr] * 256))[cc];
    }
    __syncthreads();
    stepA(0, ydB); stepB(6, 1, ydA);  __syncthreads();
    stepA(1, ydA); stepB(0, 16, ydB); __syncthreads();
    stepA(2, ydB); stepB(1, 16, ydA); __syncthreads();
    stepA(3, ydA); stepB(2, 16, ydB); __syncthreads();
    stepA(4, ydB); stepB(3, 16, ydA); __syncthreads();
    stepA(5, ydA); stepB(4, 16, ydB); __syncthreads();
    stepB(5, 16, ydA);
    __syncthreads();
  }

  // ===== P8: head (reads spl; scratch in dead bufA region) =====
  {
    float* y1  = (float*)(arena);           // [16][30]  1920 B
    float* yp  = (float*)(arena + 2048);    // [16][15]  960 B
    float* yc  = (float*)(arena + 3072);    // [32][11]  1408 B
    float* red = (float*)(arena + 4608);    // [1024]    4096 B
    for (int idx = t; idx < 16 * 30; idx += 1024) {
      int c = idx / 30, kk = idx - c * 30;
      float a = c1b[c];
      for (int d = 0; d < 97; d++) a += spl[kk * 97 + d] * c1W[c * 97 + d];
      y1[c * 30 + kk] = fmaxf(a, 0.f);
    }
    __syncthreads();
    for (int idx = t; idx < 16 * 15; idx += 1024) {
      int c = idx / 15, t2 = idx - c * 15;
      yp[idx] = fmaxf(y1[c * 30 + 2 * t2], y1[c * 30 + 2 * t2 + 1]);
    }
    __syncthreads();
    for (int idx = t; idx < 32 * 11; idx += 1024) {
      int o = idx / 11, t3 = idx - o * 11;
      float a = c2b[o];
      for (int i2 = 0; i2 < 16; i2++)
        for (int ww = 0; ww < 5; ww++)
          a += yp[i2 * 15 + t3 + ww] * c2W[(o * 16 + i2) * 5 + ww];
      yc[o * 11 + t3] = fmaxf(a, 0.f);
    }
    __syncthreads();
    {
      int o = t & 31, g = t >> 5;   // 32 outputs x 32 groups of 11
      float a = 0.f;
      for (int qq = g * 11; qq < g * 11 + 11; qq++) a += yc[qq] * oW[qq * 32 + o];
      red[t] = a;
    }
    __syncthreads();
    if (t < 32) {
      float a = ob[t];
      #pragma unroll
      for (int g = 0; g < 32; g++) a += red[t + 32 * g];
      out[(size_t)b * 32 + t] = fmaxf(a, 0.f);
    }
  }
}

extern "C" void kernel_launch(void* const* d_in, const int* in_sizes, int n_in,
                              void* d_out, int out_size, void* d_ws, size_t ws_size,
                              hipStream_t stream) {
  const float* x   = (const float*)d_in[0];
  const float* A0  = (const float*)d_in[1];
  const float* dW0 = (const float*)d_in[2];
  const float* db0 = (const float*)d_in[3];
  const float* dW  = (const float*)d_in[4];
  const float* dbv = (const float*)d_in[5];
  const float* pp  = (const float*)d_in[6];
  const float* uW  = (const float*)d_in[7];
  const float* ub  = (const float*)d_in[8];
  const float* uWl = (const float*)d_in[9];
  const float* ubl = (const float*)d_in[10];
  const float* c1W = (const float*)d_in[11];
  const float* c1b = (const float*)d_in[12];
  const float* c2W = (const float*)d_in[13];
  const float* c2b = (const float*)d_in[14];
  const float* oW  = (const float*)d_in[15];
  const float* ob  = (const float*)d_in[16];
  float* out = (float*)d_out;

  float* base = (float*)d_ws;
  size_t off = 0;
  auto alloc = [&](size_t nel) { nel = (nel + 3) & ~(size_t)3; float* p = base + off; off += nel; return p; };
  float* H0 = alloc((size_t)BATCH * 256 * HID);
  float* H1 = alloc((size_t)BATCH * 128 * HID);
  float* D1 = alloc((size_t)BATCH * 128);
  unsigned short* Abf0 = (unsigned short*)alloc((size_t)BATCH * 256 * 256 / 2);
  unsigned short* Abf1 = (unsigned short*)alloc((size_t)BATCH * 128 * 128 / 2);
  unsigned short* Wp   = (unsigned short*)alloc((size_t)3 * WTOT / 2 + 4);

  // 1. weight planes (shared across batches)
  k_splitW3<<<(WTOT + 255) / 256, 256, 0, stream>>>(dW0, dW, uW, uWl, Wp);

  // 2. the whole network: one block per batch
  k_gunet<<<BATCH, 1024, 0, stream>>>(x, A0, Wp, db0, dW, dbv, pp, uW, ub, ubl,
                                      c1W, c1b, c2W, c2b, oW, ob,
                                      Abf0, Abf1, H0, H1, D1, out);
}

// Round 9
// 374.503 us; speedup vs baseline: 1.0149x; 1.0149x over previous
//
#include <hip/hip_runtime.h>
#include <math.h>

#define BATCH 256
#define NNODE 256
#define FIN   128
#define HID   48
#define DOUT  97

// packed transposed weight planes (ushort elements, per-plane offsets)
#define WOFF_DW0 0        // dW0^T [48][128]
#define WOFF_DW  6144     // dW[i]^T 4 x [48][64]
#define WOFF_UW  18432    // uW[i]^T 3 x [48][64]
#define WOFF_UWL 27648    // uWl^T  [112][64]
#define WTOT     34816    // per-plane stride

typedef __attribute__((ext_vector_type(8))) short bf16x8_t;
typedef __attribute__((ext_vector_type(4))) float f32x4_t;

__device__ inline unsigned short f2bf(float x) {
  unsigned u = __float_as_uint(x);
  u += 0x7fff + ((u >> 16) & 1);
  return (unsigned short)(u >> 16);
}
__device__ inline float bf2f(unsigned short h) {
  return __uint_as_float(((unsigned)h) << 16);
}

template<int L> __device__ inline float grp_sum(float v) {
  #pragma unroll
  for (int o = L >> 1; o > 0; o >>= 1) v += __shfl_xor(v, o);
  return v;
}
template<int L> __device__ inline int grp_isum(int v) {
  #pragma unroll
  for (int o = L >> 1; o > 0; o >>= 1) v += __shfl_xor(v, o);
  return v;
}

// ---------- fused A0 pass: bf16 convert + rowsum -> dinv (exact: 0/1 entries) ----------
__global__ __launch_bounds__(256) void k_prepA(const float* __restrict__ A,
                                               unsigned short* __restrict__ Abf,
                                               float* __restrict__ dinv, int rows) {
  int wid = (blockIdx.x * 256 + threadIdx.x) >> 6;
  int lane = threadIdx.x & 63;
  if (wid >= rows) return;
  const float4* rp = (const float4*)(A + (size_t)wid * 256);
  float4 v = rp[lane];
  unsigned long long pk = (unsigned long long)f2bf(v.x)
                        | ((unsigned long long)f2bf(v.y) << 16)
                        | ((unsigned long long)f2bf(v.z) << 32)
                        | ((unsigned long long)f2bf(v.w) << 48);
  *(unsigned long long*)(Abf + (size_t)wid * 256 + lane * 4) = pk;
  float s = v.x + v.y + v.z + v.w;
  #pragma unroll
  for (int o = 32; o > 0; o >>= 1) s += __shfl_down(s, o);
  if (lane == 0) dinv[wid] = 1.0f / sqrtf(s + 2.0f);
}

// ---------- transpose + 3-plane split ALL weights (runs once, tiny) ----------
__global__ __launch_bounds__(256) void k_splitW3(const float* __restrict__ dW0,
                                                 const float* __restrict__ dW,
                                                 const float* __restrict__ uW,
                                                 const float* __restrict__ uWl,
                                                 unsigned short* __restrict__ Wp) {
  int idx = blockIdx.x * 256 + threadIdx.x;
  if (idx >= WTOT) return;
  float v;
  if (idx < WOFF_DW) {                   // dW0^T [48][128]
    int f = idx / 128, kk = idx - f * 128;
    v = dW0[kk * HID + f];
  } else if (idx < WOFF_UW) {            // dW[i]^T [48][64]
    int r = idx - WOFF_DW;
    int i = r / 3072; r -= i * 3072;
    int f = r / 64, kk = r - f * 64;
    v = (kk < HID) ? dW[((size_t)i * HID + kk) * HID + f] : 0.f;
  } else if (idx < WOFF_UWL) {           // uW[i]^T [48][64]
    int r = idx - WOFF_UW;
    int i = r / 3072; r -= i * 3072;
    int f = r / 64, kk = r - f * 64;
    v = (kk < HID) ? uW[((size_t)i * HID + kk) * HID + f] : 0.f;
  } else {                               // uWl^T [112][64]
    int r = idx - WOFF_UWL;
    int f = r / 64, kk = r - f * 64;
    v = (f < DOUT && kk < HID) ? uWl[(size_t)kk * DOUT + f] : 0.f;
  }
  unsigned short h = f2bf(v);
  float r1 = v - bf2f(h);
  unsigned short m = f2bf(r1);
  float r2 = r1 - bf2f(m);
  unsigned short l = f2bf(r2);
  Wp[idx] = h;
  Wp[idx + WTOT] = m;
  Wp[idx + 2 * WTOT] = l;
}

// ---------- fused first GCN (n=256, K=128): 16 waves, 1 m-tile / it-tile per wave ----------
// MFMA chains split into 2 accumulators (acc[ks&1]) to halve dependent-MFMA latency.
__global__ __launch_bounds__(1024) void k_big(const float* __restrict__ x,
                                              const unsigned short* __restrict__ Wp0,
                                              const unsigned short* __restrict__ Abf0,
                                              const float* __restrict__ D0,
                                              const float* __restrict__ db0,
                                              float* __restrict__ H0) {
  __shared__ __align__(16) char yt0[24576];   // XWdT hi [48][256] bf16, swizzled
  __shared__ __align__(16) char yt1[24576];   // XWdT lo
  int b = blockIdx.x, t = threadIdx.x;
  int w = t >> 6, lane = t & 63;
  int r = lane & 15, q = lane >> 4;
  const float* Xb = x + (size_t)b * 256 * 128;
  const float* Db = D0 + (size_t)b * 256;
  // ---- step A ----
  {
    int m = w;
    const float* xr = Xb + (size_t)(m * 16 + r) * 128;
    bf16x8_t ah[4], am[4], al[4];
    #pragma unroll
    for (int ks = 0; ks < 4; ks++) {
      int col0 = ks * 32 + q * 8;
      float4 a4 = *(const float4*)(xr + col0);
      float4 b4 = *(const float4*)(xr + col0 + 4);
      float v[8] = {a4.x, a4.y, a4.z, a4.w, b4.x, b4.y, b4.z, b4.w};
      #pragma unroll
      for (int j = 0; j < 8; j++) {
        unsigned short h = f2bf(v[j]); float r1 = v[j] - bf2f(h);
        unsigned short mm = f2bf(r1);  float r2 = r1 - bf2f(mm);
        ah[ks][j] = (short)h; am[ks][j] = (short)mm; al[ks][j] = (short)f2bf(r2);
      }
    }
    int row0 = m * 16 + q * 4;
    float4 dv4 = *(const float4*)(Db + row0);
    float dvv[4] = {dv4.x, dv4.y, dv4.z, dv4.w};
    #pragma unroll
    for (int ft = 0; ft < 3; ft++) {
      int fl = ft * 16 + r;
      const unsigned short* wb = Wp0 + (size_t)fl * 128 + q * 8;
      f32x4_t accv[2] = {{0.f,0.f,0.f,0.f},{0.f,0.f,0.f,0.f}};
      #pragma unroll
      for (int ks = 0; ks < 4; ks++) {
        bf16x8_t bh = *(const bf16x8_t*)(wb + ks * 32);
        bf16x8_t bm = *(const bf16x8_t*)(wb + WTOT + ks * 32);
        bf16x8_t bl = *(const bf16x8_t*)(wb + 2 * WTOT + ks * 32);
        accv[ks & 1] = __builtin_amdgcn_mfma_f32_16x16x32_bf16(ah[ks], bh, accv[ks & 1], 0, 0, 0);
        accv[ks & 1] = __builtin_amdgcn_mfma_f32_16x16x32_bf16(ah[ks], bm, accv[ks & 1], 0, 0, 0);
        accv[ks & 1] = __builtin_amdgcn_mfma_f32_16x16x32_bf16(am[ks], bh, accv[ks & 1], 0, 0, 0);
        accv[ks & 1] = __builtin_amdgcn_mfma_f32_16x16x32_bf16(am[ks], bm, accv[ks & 1], 0, 0, 0);
        accv[ks & 1] = __builtin_amdgcn_mfma_f32_16x16x32_bf16(ah[ks], bl, accv[ks & 1], 0, 0, 0);
        accv[ks & 1] = __builtin_amdgcn_mfma_f32_16x16x32_bf16(al[ks], bh, accv[ks & 1], 0, 0, 0);
      }
      f32x4_t acc = accv[0] + accv[1];
      #pragma unroll
      for (int reg = 0; reg < 4; reg++) {
        float vv = dvv[reg] * acc[reg];
        unsigned short hi = f2bf(vv);
        unsigned short lo = f2bf(vv - bf2f(hi));
        int byte = (fl * 512 + (row0 + reg) * 2) ^ ((fl & 7) << 4);
        *(unsigned short*)(yt0 + byte) = hi;
        *(unsigned short*)(yt1 + byte) = lo;
      }
    }
  }
  __syncthreads();
  // ---- step B ----
  {
    int it = w;
    const unsigned short* ap = Abf0 + ((size_t)b * 256 + it * 16 + r) * 256 + q * 8;
    bf16x8_t af[8];
    #pragma unroll
    for (int ks = 0; ks < 8; ks++) af[ks] = *(const bf16x8_t*)(ap + ks * 32);
    #pragma unroll
    for (int ft = 0; ft < 3; ft++) {
      int fl = ft * 16 + r;
      f32x4_t accv[2] = {{0.f,0.f,0.f,0.f},{0.f,0.f,0.f,0.f}};
      #pragma unroll
      for (int ks = 0; ks < 8; ks++) {
        int byte = (fl * 512 + (ks * 32 + q * 8) * 2) ^ ((fl & 7) << 4);
        bf16x8_t bh = *(const bf16x8_t*)(yt0 + byte);
        bf16x8_t bl = *(const bf16x8_t*)(yt1 + byte);
        accv[ks & 1] = __builtin_amdgcn_mfma_f32_16x16x32_bf16(af[ks], bh, accv[ks & 1], 0, 0, 0);
        accv[ks & 1] = __builtin_amdgcn_mfma_f32_16x16x32_bf16(af[ks], bl, accv[ks & 1], 0, 0, 0);
      }
      f32x4_t acc = accv[0] + accv[1];
      float bfv = db0[fl];
      #pragma unroll
      for (int reg = 0; reg < 4; reg++) {
        int rr = it * 16 + q * 4 + reg;
        int sbyte = (fl * 512 + rr * 2) ^ ((fl & 7) << 4);
        float selfv = bf2f(*(const unsigned short*)(yt0 + sbyte))
                    + bf2f(*(const unsigned short*)(yt1 + sbyte));
        float d = Db[rr];
        float v = d * acc[reg] + 2.f * d * selfv + bfv;
        H0[((size_t)b * 256 + rr) * 48 + fl] = fmaxf(v, 0.f);
      }
    }
  }
}

// ---------- GCN@128 phase (1024 threads): 24 (m,ft) tasks per step ----------
template<int MODE>
__device__ inline void gcn128_phase(const float* __restrict__ Xg,
                                    const unsigned short* __restrict__ Wpl,
                                    const unsigned short* __restrict__ A1,
                                    const float* __restrict__ D1b,
                                    const float* __restrict__ bias,
                                    char* yt0, char* yt1,
                                    float* __restrict__ H1,
                                    float* __restrict__ H0b,
                                    const int* sPerm1, int t) {
  int w = t >> 6, lane = t & 63;
  int r = lane & 15, q = lane >> 4;
  // step A
  for (int task = w; task < 24; task += 16) {
    int m = task / 3, ft = task - m * 3;
    const float* xr = Xg + (size_t)(m * 16 + r) * 48;
    bf16x8_t ah[2], am[2], al[2];
    #pragma unroll
    for (int ks = 0; ks < 2; ks++) {
      int col0 = ks * 32 + q * 8;
      float v[8];
      if (col0 + 8 <= 48) {
        float4 a4 = *(const float4*)(xr + col0);
        float4 b4 = *(const float4*)(xr + col0 + 4);
        v[0]=a4.x; v[1]=a4.y; v[2]=a4.z; v[3]=a4.w;
        v[4]=b4.x; v[5]=b4.y; v[6]=b4.z; v[7]=b4.w;
      } else {
        #pragma unroll
        for (int j = 0; j < 8; j++) v[j] = (col0 + j < 48) ? xr[col0 + j] : 0.f;
      }
      #pragma unroll
      for (int j = 0; j < 8; j++) {
        unsigned short h = f2bf(v[j]); float r1 = v[j] - bf2f(h);
        unsigned short mm = f2bf(r1);  float r2 = r1 - bf2f(mm);
        ah[ks][j] = (short)h; am[ks][j] = (short)mm; al[ks][j] = (short)f2bf(r2);
      }
    }
    int row0 = m * 16 + q * 4;
    float4 dv4 = *(const float4*)(D1b + row0);
    float dvv[4] = {dv4.x, dv4.y, dv4.z, dv4.w};
    int fl = ft * 16 + r;
    const unsigned short* wb = Wpl + (size_t)fl * 64 + q * 8;
    f32x4_t accv[2] = {{0.f,0.f,0.f,0.f},{0.f,0.f,0.f,0.f}};
    #pragma unroll
    for (int ks = 0; ks < 2; ks++) {
      bf16x8_t bh = *(const bf16x8_t*)(wb + ks * 32);
      bf16x8_t bm = *(const bf16x8_t*)(wb + WTOT + ks * 32);
      bf16x8_t bl = *(const bf16x8_t*)(wb + 2 * WTOT + ks * 32);
      accv[ks] = __builtin_amdgcn_mfma_f32_16x16x32_bf16(ah[ks], bh, accv[ks], 0, 0, 0);
      accv[ks] = __builtin_amdgcn_mfma_f32_16x16x32_bf16(ah[ks], bm, accv[ks], 0, 0, 0);
      accv[ks] = __builtin_amdgcn_mfma_f32_16x16x32_bf16(am[ks], bh, accv[ks], 0, 0, 0);
      accv[ks] = __builtin_amdgcn_mfma_f32_16x16x32_bf16(am[ks], bm, accv[ks], 0, 0, 0);
      accv[ks] = __builtin_amdgcn_mfma_f32_16x16x32_bf16(ah[ks], bl, accv[ks], 0, 0, 0);
      accv[ks] = __builtin_amdgcn_mfma_f32_16x16x32_bf16(al[ks], bh, accv[ks], 0, 0, 0);
    }
    f32x4_t acc = accv[0] + accv[1];
    #pragma unroll
    for (int reg = 0; reg < 4; reg++) {
      float vv = dvv[reg] * acc[reg];
      unsigned short hi = f2bf(vv);
      unsigned short lo = f2bf(vv - bf2f(hi));
      int byte = (fl * 256 + (row0 + reg) * 2) ^ ((fl & 7) << 4);
      *(unsigned short*)(yt0 + byte) = hi;
      *(unsigned short*)(yt1 + byte) = lo;
    }
  }
  __syncthreads();
  // step B
  for (int task = w; task < 24; task += 16) {
    int it = task / 3, ft = task - it * 3;
    const unsigned short* ap = A1 + (size_t)(it * 16 + r) * 128 + q * 8;
    bf16x8_t af[4];
    #pragma unroll
    for (int ks = 0; ks < 4; ks++) af[ks] = *(const bf16x8_t*)(ap + ks * 32);
    int fl = ft * 16 + r;
    f32x4_t accv[2] = {{0.f,0.f,0.f,0.f},{0.f,0.f,0.f,0.f}};
    #pragma unroll
    for (int ks = 0; ks < 4; ks++) {
      int byte = (fl * 256 + (ks * 32 + q * 8) * 2) ^ ((fl & 7) << 4);
      bf16x8_t bh = *(const bf16x8_t*)(yt0 + byte);
      bf16x8_t bl = *(const bf16x8_t*)(yt1 + byte);
      accv[ks & 1] = __builtin_amdgcn_mfma_f32_16x16x32_bf16(af[ks], bh, accv[ks & 1], 0, 0, 0);
      accv[ks & 1] = __builtin_amdgcn_mfma_f32_16x16x32_bf16(af[ks], bl, accv[ks & 1], 0, 0, 0);
    }
    f32x4_t acc = accv[0] + accv[1];
    float bfv = bias[fl];
    #pragma unroll
    for (int reg = 0; reg < 4; reg++) {
      int rr = it * 16 + q * 4 + reg;
      int sbyte = (fl * 256 + rr * 2) ^ ((fl & 7) << 4);
      float selfv = bf2f(*(const unsigned short*)(yt0 + sbyte))
                  + bf2f(*(const unsigned short*)(yt1 + sbyte));
      float d = D1b[rr];
      float v = d * acc[reg] + 2.f * d * selfv + bfv;
      v = fmaxf(v, 0.f);
      if (MODE == 0) H1[(size_t)rr * 48 + fl] = v;
      else {
        int node = sPerm1[rr];
        H0b[(size_t)node * 48 + fl] += v;
      }
    }
  }
  __syncthreads();
}

// ---------- inner-U device helpers (1024-thread), 4-way split accumulators ----------
__device__ inline void xw_dphase(const float* hin, const float* W, const float* dv,
                                 float* xwd, int n, int t) {
  for (int idx = t; idx < n * 48; idx += 1024) {
    int j = idx / 48, f = idx - j * 48;
    const float* hr = hin + j * 48;
    float a0 = 0.f, a1 = 0.f, a2 = 0.f, a3 = 0.f;
    #pragma unroll
    for (int g = 0; g < 48; g += 4) {
      a0 += hr[g]     * W[g * 48 + f];
      a1 += hr[g + 1] * W[(g + 1) * 48 + f];
      a2 += hr[g + 2] * W[(g + 2) * 48 + f];
      a3 += hr[g + 3] * W[(g + 3) * 48 + f];
    }
    xwd[idx] = dv[j] * ((a0 + a1) + (a2 + a3));
  }
}

__device__ inline void anxw_phase(const float* A, int lda, const float* xwd,
                                  const float* dv, const float* bias,
                                  float* hout, int n, int t) {
  for (int idx = t; idx < n * 48; idx += 1024) {
    int i = idx / 48, f = idx - i * 48;
    const float* ar = A + i * lda;
    float a0 = 0.f, a1 = 0.f, a2 = 0.f, a3 = 0.f;
    for (int j = 0; j < n; j += 4) {
      a0 += ar[j]     * xwd[j * 48 + f];
      a1 += ar[j + 1] * xwd[(j + 1) * 48 + f];
      a2 += ar[j + 2] * xwd[(j + 2) * 48 + f];
      a3 += ar[j + 3] * xwd[(j + 3) * 48 + f];
    }
    float acc = (a0 + a1) + (a2 + a3);
    float di = dv[i];
    float v = di * acc + 2.f * di * xwd[i * 48 + f] + bias[f];
    hout[idx] = fmaxf(v, 0.f);
  }
}

// pool + aug fused: score, rank, {gather || aug-dot}, dinv
template<int N, int K>
__device__ inline void pool_aug_phaseT(const float* h, const float* p,
                                       const float* A, int lda,
                                       float* Ao, int ldo,
                                       float* sS, int* perm, float* hin,
                                       float* dout, int t) {
  constexpr int LPR = 1024 / N;
  int row = t / LPR, sub = t % LPR;
  float pn = 0.f;
  #pragma unroll
  for (int g = 0; g < 48; g++) pn += p[g] * p[g];
  const float* hr = h + row * 48;
  float acc = 0.f;
  for (int g = sub; g < 48; g += LPR) acc += hr[g] * p[g];
  acc = grp_sum<LPR>(acc);
  if (sub == 0) sS[row] = tanhf(acc / sqrtf(pn));
  __syncthreads();
  {
    float v = sS[row];
    int rk = 0;
    for (int j = sub; j < N; j += LPR) {
      float u = sS[j];
      rk += (u > v) || (u == v && j < row);
    }
    rk = grp_isum<LPR>(rk);
    if (sub == 0 && rk < K) perm[rk] = row;
  }
  __syncthreads();
  for (int idx = t; idx < K * 48; idx += 1024) {
    int r = idx / 48, g = idx - r * 48;
    int pi = perm[r];
    hin[idx] = h[pi * 48 + g] * sS[pi];
  }
  for (int idx = t; idx < K * K; idx += 1024) {
    int r = idx / K, c = idx - r * K;
    int pr = perm[r], pc = perm[c];
    const float* ra = A + pr * lda;
    const float* rc = A + pc * lda;
    float a0 = 0.f, a1 = 0.f, a2 = 0.f, a3 = 0.f;
    for (int j = 0; j < N; j += 4) {
      a0 += ra[j]     * rc[j];
      a1 += ra[j + 1] * rc[j + 1];
      a2 += ra[j + 2] * rc[j + 2];
      a3 += ra[j + 3] * rc[j + 3];
    }
    float v = ((a0 + a1) + (a2 + a3)) + 2.f * ra[pc];
    Ao[r * ldo + c] = (r == c) ? 0.f : v;
  }
  __syncthreads();
  {
    constexpr int LPR2 = 1024 / K;
    constexpr int LG = (LPR2 > 64 ? 64 : LPR2);
    int row2 = t / LPR2, sub2 = t % LPR2;
    float s = 0.f;
    for (int j = sub2; j < K; j += LPR2) s += Ao[row2 * ldo + j];
    s = grp_sum<LG>(s);
    if (sub2 == 0) dout[row2] = 1.0f / sqrtf(s + 2.0f);
  }
  __syncthreads();
}

__device__ inline void scat_phase(const int* perm, const float* src, float* dst,
                                  int k, int t) {
  for (int idx = t; idx < k * 48; idx += 1024) {
    int r = idx / 48, g = idx - r * 48;
    dst[perm[r] * 48 + g] += src[idx];
  }
  __syncthreads();
}

// ========== k_mid: pool0 + aug1(+D1) + enc GCN@128 + inner U + dec GCN@128 + scatter H0 ==========
__global__ __launch_bounds__(1024) void k_mid(const unsigned short* __restrict__ Abf0,
                                              unsigned short* __restrict__ Abf1g,
                                              float* __restrict__ H0,
                                              float* __restrict__ H1g,
                                              float* __restrict__ D1g,
                                              const unsigned short* __restrict__ Wp,
                                              const float* __restrict__ dW,
                                              const float* __restrict__ dbv,
                                              const float* __restrict__ pp,
                                              const float* __restrict__ uW,
                                              const float* __restrict__ ub) {
  int b = blockIdx.x, t = threadIdx.x;
  __shared__ __align__(16) char arena[63488];
  __shared__ int sPerm1[128];
  float* H1 = H1g + (size_t)b * 128 * 48;
  float* H0b = H0 + (size_t)b * 256 * 48;
  unsigned short* A1 = Abf1g + (size_t)b * 128 * 128;
  float* D1b = D1g + (size_t)b * 128;
  int w = t >> 6, lane = t & 63;
  int r = lane & 15, q = lane >> 4;

  // ===== P0: pool0 scores + rank =====
  {
    float* sc = (float*)arena;
    const float* p = pp;
    float pn = 0.f;
    #pragma unroll
    for (int g = 0; g < 48; g++) pn += p[g] * p[g];
    int row = t >> 2, sub = t & 3;
    const float* hr = H0b + (size_t)row * 48;
    float a = 0.f;
    for (int g = sub; g < 48; g += 4) a += hr[g] * p[g];
    a = grp_sum<4>(a);
    if (!sub) sc[row] = tanhf(a / sqrtf(pn));
    __syncthreads();
    float vv = sc[row];
    int rk = 0;
    for (int j = sub; j < 256; j += 4) {
      float u = sc[j];
      rk += (u > vv) || (u == vv && j < row);
    }
    rk = grp_isum<4>(rk);
    if (!sub && rk < 128) sPerm1[rk] = row;
  }
  __syncthreads();

  // ===== P1: gather into H1 (memory) || aug1 MFMA (2-acc chains) =====
  {
    float* sc = (float*)arena;
    for (int idx = t; idx < 128 * 48; idx += 1024) {
      int rr = idx / 48, g = idx - rr * 48;
      int pi = sPerm1[rr];
      H1[idx] = H0b[(size_t)pi * 48 + g] * sc[pi];
    }
    int it = w >> 1, fh = w & 1;
    int rowA = sPerm1[it * 16 + r];
    const unsigned short* Ab = Abf0 + (size_t)b * 256 * 256;
    const unsigned short* pa = Ab + (size_t)rowA * 256 + q * 8;
    bf16x8_t af[8];
    #pragma unroll
    for (int ks = 0; ks < 8; ks++) {
      bf16x8_t a = *(const bf16x8_t*)(pa + ks * 32);
      int da = rowA - ks * 32 - q * 8;
      #pragma unroll
      for (int e = 0; e < 8; e++) if (da == e) a[e] = (short)0x3F80;
      af[ks] = a;
    }
    for (int ft = fh * 4; ft < fh * 4 + 4; ft++) {
      int rowB = sPerm1[ft * 16 + r];
      const unsigned short* pb = Ab + (size_t)rowB * 256 + q * 8;
      f32x4_t accv[2] = {{0.f,0.f,0.f,0.f},{0.f,0.f,0.f,0.f}};
      #pragma unroll
      for (int ks = 0; ks < 8; ks++) {
        bf16x8_t bv = *(const bf16x8_t*)(pb + ks * 32);
        int db_ = rowB - ks * 32 - q * 8;
        #pragma unroll
        for (int e = 0; e < 8; e++) if (db_ == e) bv[e] = (short)0x3F80;
        accv[ks & 1] = __builtin_amdgcn_mfma_f32_16x16x32_bf16(af[ks], bv, accv[ks & 1], 0, 0, 0);
      }
      f32x4_t acc = accv[0] + accv[1];
      int c = ft * 16 + r;
      #pragma unroll
      for (int reg = 0; reg < 4; reg++) {
        int rr = it * 16 + q * 4 + reg;
        float v = (rr == c) ? 0.f : acc[reg];
        A1[(size_t)rr * 128 + c] = f2bf(v);
      }
    }
  }
  __syncthreads();
  // D1 rowsum from bf16 A1 (exact); 8 lanes/row
  {
    int row = t >> 3, sub = t & 7;
    const unsigned* ar = (const unsigned*)(A1 + (size_t)row * 128);
    float s = 0.f;
    for (int jj = sub; jj < 64; jj += 8) {
      unsigned u = ar[jj];
      s += bf2f((unsigned short)(u & 0xffffu)) + bf2f((unsigned short)(u >> 16));
    }
    s = grp_sum<8>(s);
    if (sub == 0) D1b[row] = 1.0f / sqrtf(s + 2.0f);
  }
  __syncthreads();

  // ===== P2: encoder GCN@128 (dW[0], db[0]) -> H1 =====
  gcn128_phase<0>(H1, Wp + WOFF_DW, A1, D1b, dbv,
                  arena, arena + 12288, H1, nullptr, sPerm1, t);

  // ===== P3: inner U =====
  {
    float* sS  = (float*)(arena);
    int*   sP2 = (int*)(arena + 512);
    int*   sP3 = (int*)(arena + 768);
    int*   sP4 = (int*)(arena + 896);
    float* sD2 = (float*)(arena + 960);
    float* sD3 = (float*)(arena + 1216);
    float* sD4 = (float*)(arena + 1344);
    float* sA2 = (float*)(arena + 1536);    // [64][65]
    float* sA3 = (float*)(arena + 18176);   // [32][33]
    float* sH2 = (float*)(arena + 22400);   // [64][48]
    float* sH3 = (float*)(arena + 34688);   // [32][48]
    float* sXW = (float*)(arena + 40832);   // [64][48]
    float* hin = (float*)(arena + 53120);   // [32][48]
    float* sH4 = (float*)(arena + 59264);   // [16][48]
    float* sA4 = (float*)(arena + 62336);   // [16][17]

    // lvl1 pool scores + rank (n=128 -> k=64), LPR=8
    {
      const float* p = pp + 48;
      float pn = 0.f;
      #pragma unroll
      for (int g = 0; g < 48; g++) pn += p[g] * p[g];
      int row = t >> 3, sub = t & 7;
      const float* hr = H1 + (size_t)row * 48;
      float acc = 0.f;
      for (int g = sub; g < 48; g += 8) acc += hr[g] * p[g];
      acc = grp_sum<8>(acc);
      if (sub == 0) sS[row] = tanhf(acc / sqrtf(pn));
      __syncthreads();
      float v = sS[row];
      int rk = 0;
      for (int j = sub; j < 128; j += 8) {
        float u = sS[j];
        rk += (u > v) || (u == v && j < row);
      }
      rk = grp_isum<8>(rk);
      if (sub == 0 && rk < 64) sP2[rk] = row;
      __syncthreads();
    }
    // aug: A2 via MFMA from global A1 (2-acc chains); 1 tile/wave
    {
      int it = w >> 2, ft = w & 3;
      int rowA = sP2[it * 16 + r];
      int rowB = sP2[ft * 16 + r];
      const unsigned short* pa = A1 + (size_t)rowA * 128 + q * 8;
      const unsigned short* pb = A1 + (size_t)rowB * 128 + q * 8;
      f32x4_t accv[2] = {{0.f,0.f,0.f,0.f},{0.f,0.f,0.f,0.f}};
      #pragma unroll
      for (int k0 = 0; k0 < 4; k0++) {
        bf16x8_t a  = *(const bf16x8_t*)(pa + k0 * 32);
        bf16x8_t bv = *(const bf16x8_t*)(pb + k0 * 32);
        int daA = rowA - k0 * 32 - q * 8;
        int daB = rowB - k0 * 32 - q * 8;
        #pragma unroll
        for (int e = 0; e < 8; e++) {
          if (daA == e) a[e] = (short)0x3F80;
          if (daB == e) bv[e] = (short)0x3F80;
        }
        accv[k0 & 1] = __builtin_amdgcn_mfma_f32_16x16x32_bf16(a, bv, accv[k0 & 1], 0, 0, 0);
      }
      f32x4_t acc = accv[0] + accv[1];
      int c = ft * 16 + r;
      #pragma unroll
      for (int reg = 0; reg < 4; reg++) {
        int rr = it * 16 + q * 4 + reg;
        sA2[rr * 65 + c] = (rr == c) ? 0.f : acc[reg];
      }
    }
    __syncthreads();
    // D2 rowsum (LPR=16)
    {
      int row = t >> 4, sub = t & 15;
      float s = 0.f;
      for (int j = sub; j < 64; j += 16) s += sA2[row * 65 + j];
      s = grp_sum<16>(s);
      if (sub == 0) sD2[row] = 1.0f / sqrtf(s + 2.0f);
    }
    __syncthreads();
    // lvl1 XWd: gather-fold from H1 global, 4-acc
    for (int idx = t; idx < 64 * 48; idx += 1024) {
      int j = idx / 48, f = idx - j * 48;
      int pi = sP2[j];
      const float* hr = H1 + (size_t)pi * 48;
      const float* W = dW + 2304;
      float a0 = 0.f, a1 = 0.f, a2 = 0.f, a3 = 0.f;
      #pragma unroll
      for (int g = 0; g < 48; g += 4) {
        a0 += hr[g]     * W[g * 48 + f];
        a1 += hr[g + 1] * W[(g + 1) * 48 + f];
        a2 += hr[g + 2] * W[(g + 2) * 48 + f];
        a3 += hr[g + 3] * W[(g + 3) * 48 + f];
      }
      sXW[idx] = sD2[j] * sS[pi] * ((a0 + a1) + (a2 + a3));
    }
    __syncthreads();
    anxw_phase(sA2, 65, sXW, sD2, dbv + 48, sH2, 64, t);
    __syncthreads();

    // lvl2 (64 -> 32)
    pool_aug_phaseT<64, 32>(sH2, pp + 96, sA2, 65, sA3, 33, sS, sP3, hin, sD3, t);
    xw_dphase(hin, dW + 2 * 2304, sD3, sXW, 32, t);
    __syncthreads();
    anxw_phase(sA3, 33, sXW, sD3, dbv + 96, sH3, 32, t);
    __syncthreads();

    // lvl3 (32 -> 16)
    pool_aug_phaseT<32, 16>(sH3, pp + 144, sA3, 33, sA4, 17, sS, sP4, hin, sD4, t);
    xw_dphase(hin, dW + 3 * 2304, sD4, sXW, 16, t);
    __syncthreads();
    anxw_phase(sA4, 17, sXW, sD4, dbv + 144, sH4, 16, t);
    __syncthreads();

    // dec j=3
    scat_phase(sP4, sH4, sH3, 16, t);
    xw_dphase(sH3, uW, sD3, sXW, 32, t);
    __syncthreads();
    anxw_phase(sA3, 33, sXW, sD3, ub, sH3, 32, t);
    __syncthreads();

    // dec j=2
    scat_phase(sP3, sH3, sH2, 32, t);
    xw_dphase(sH2, uW + 2304, sD2, sXW, 64, t);
    __syncthreads();
    anxw_phase(sA2, 65, sXW, sD2, ub + 48, sH2, 64, t);
    __syncthreads();

    // H1 += up(sH2)
    for (int idx = t; idx < 64 * 48; idx += 1024) {
      int r2 = idx / 48, g = idx - r2 * 48;
      H1[(size_t)sP2[r2] * 48 + g] += sH2[idx];
    }
  }
  __syncthreads();

  // ===== P4: decoder GCN@128 (uW[2], ub[2]) -> scatter-add into H0 =====
  gcn128_phase<1>(H1, Wp + WOFF_UW + 2 * 3072, A1, D1b, ub + 96,
                  arena, arena + 12288, nullptr, H0b, sPerm1, t);
}

// ========== k_tail: fused final GCN (uWl) — yd tiles fp32 LDS, no Yt round-trip ==========
__global__ __launch_bounds__(1024) void k_tail(const float* __restrict__ H0,
                                               const unsigned short* __restrict__ Wpl,
                                               const unsigned short* __restrict__ Abf,
                                               const float* __restrict__ dinv,
                                               const float* __restrict__ ubl,
                                               float* __restrict__ sp) {
  int b = blockIdx.x, t = threadIdx.x;
  __shared__ float ydt[16][257];
  __shared__ float sc[256];
  __shared__ int sord[32];
  int w = t >> 6, lane = t & 63;
  int r = lane & 15, q = lane >> 4;
  const float* H0b = H0 + (size_t)b * 256 * 48;
  const float* Db = dinv + (size_t)b * 256;

  bf16x8_t ah[2], am[2], al[2];
  {
    const float* xr = H0b + (size_t)(w * 16 + r) * 48;
    #pragma unroll
    for (int ks = 0; ks < 2; ks++) {
      int col0 = ks * 32 + q * 8;
      float v[8];
      if (col0 + 8 <= 48) {
        float4 a4 = *(const float4*)(xr + col0);
        float4 b4 = *(const float4*)(xr + col0 + 4);
        v[0]=a4.x; v[1]=a4.y; v[2]=a4.z; v[3]=a4.w;
        v[4]=b4.x; v[5]=b4.y; v[6]=b4.z; v[7]=b4.w;
      } else {
        #pragma unroll
        for (int j = 0; j < 8; j++) v[j] = (col0 + j < 48) ? xr[col0 + j] : 0.f;
      }
      #pragma unroll
      for (int j = 0; j < 8; j++) {
        unsigned short h = f2bf(v[j]); float r1 = v[j] - bf2f(h);
        unsigned short mm = f2bf(r1);  float r2 = r1 - bf2f(mm);
        ah[ks][j] = (short)h; am[ks][j] = (short)mm; al[ks][j] = (short)f2bf(r2);
      }
    }
  }
  int row0 = w * 16 + q * 4;
  float4 dv4 = *(const float4*)(Db + row0);
  float dvv[4] = {dv4.x, dv4.y, dv4.z, dv4.w};

  auto stepA = [&](int ft) {
    int fl = ft * 16 + r;
    const unsigned short* wb = Wpl + (size_t)fl * 64 + q * 8;
    f32x4_t accv[2] = {{0.f,0.f,0.f,0.f},{0.f,0.f,0.f,0.f}};
    #pragma unroll
    for (int ks = 0; ks < 2; ks++) {
      bf16x8_t bh = *(const bf16x8_t*)(wb + ks * 32);
      bf16x8_t bm = *(const bf16x8_t*)(wb + WTOT + ks * 32);
      bf16x8_t bl = *(const bf16x8_t*)(wb + 2 * WTOT + ks * 32);
      accv[ks] = __builtin_amdgcn_mfma_f32_16x16x32_bf16(ah[ks], bh, accv[ks], 0, 0, 0);
      accv[ks] = __builtin_amdgcn_mfma_f32_16x16x32_bf16(ah[ks], bm, accv[ks], 0, 0, 0);
      accv[ks] = __builtin_amdgcn_mfma_f32_16x16x32_bf16(am[ks], bh, accv[ks], 0, 0, 0);
      accv[ks] = __builtin_amdgcn_mfma_f32_16x16x32_bf16(am[ks], bm, accv[ks], 0, 0, 0);
      accv[ks] = __builtin_amdgcn_mfma_f32_16x16x32_bf16(ah[ks], bl, accv[ks], 0, 0, 0);
      accv[ks] = __builtin_amdgcn_mfma_f32_16x16x32_bf16(al[ks], bh, accv[ks], 0, 0, 0);
    }
    f32x4_t acc = accv[0] + accv[1];
    #pragma unroll
    for (int reg = 0; reg < 4; reg++)
      ydt[r][row0 + reg] = dvv[reg] * acc[reg];
  };

  auto stepB = [&](int ft, int nf) {
    int o = t >> 1, sub = t & 1;
    if (o < 30 * nf) {
      int rr = o / nf, f = o - rr * nf;
      int fl = ft * 16 + f;
      int node = sord[rr];
      const unsigned short* ar = Abf + ((size_t)b * 256 + node) * 256 + sub * 128;
      const float* yp = &ydt[f][sub * 128];
      float s0 = 0.f, s1 = 0.f, s2 = 0.f, s3 = 0.f;
      for (int j = 0; j < 128; j += 8) {
        unsigned u0 = *(const unsigned*)(ar + j);
        unsigned u1 = *(const unsigned*)(ar + j + 2);
        unsigned u2 = *(const unsigned*)(ar + j + 4);
        unsigned u3 = *(const unsigned*)(ar + j + 6);
        s0 += bf2f((unsigned short)(u0 & 0xffffu)) * yp[j]     + bf2f((unsigned short)(u0 >> 16)) * yp[j + 1];
        s1 += bf2f((unsigned short)(u1 & 0xffffu)) * yp[j + 2] + bf2f((unsigned short)(u1 >> 16)) * yp[j + 3];
        s2 += bf2f((unsigned short)(u2 & 0xffffu)) * yp[j + 4] + bf2f((unsigned short)(u2 >> 16)) * yp[j + 5];
        s3 += bf2f((unsigned short)(u3 & 0xffffu)) * yp[j + 6] + bf2f((unsigned short)(u3 >> 16)) * yp[j + 7];
      }
      float s = (s0 + s1) + (s2 + s3);
      s += __shfl_xor(s, 1);
      if (!sub) {
        float d = Db[node];
        sp[((size_t)b * 30 + rr) * DOUT + fl] = d * s + 2.f * d * ydt[f][node] + ubl[fl];
      }
    }
  };

  stepA(6);
  __syncthreads();
  // col-96 scores: 4 lanes per node, 4-acc
  {
    int i = t >> 2, sub = t & 3;
    const unsigned short* ar = Abf + ((size_t)b * 256 + i) * 256 + sub * 64;
    const float* yp = &ydt[0][sub * 64];
    float s0 = 0.f, s1 = 0.f, s2 = 0.f, s3 = 0.f;
    for (int j = 0; j < 64; j += 8) {
      unsigned u0 = *(const unsigned*)(ar + j);
      unsigned u1 = *(const unsigned*)(ar + j + 2);
      unsigned u2 = *(const unsigned*)(ar + j + 4);
      unsigned u3 = *(const unsigned*)(ar + j + 6);
      s0 += bf2f((unsigned short)(u0 & 0xffffu)) * yp[j]     + bf2f((unsigned short)(u0 >> 16)) * yp[j + 1];
      s1 += bf2f((unsigned short)(u1 & 0xffffu)) * yp[j + 2] + bf2f((unsigned short)(u1 >> 16)) * yp[j + 3];
      s2 += bf2f((unsigned short)(u2 & 0xffffu)) * yp[j + 4] + bf2f((unsigned short)(u2 >> 16)) * yp[j + 5];
      s3 += bf2f((unsigned short)(u3 & 0xffffu)) * yp[j + 6] + bf2f((unsigned short)(u3 >> 16)) * yp[j + 7];
    }
    float s = grp_sum<4>((s0 + s1) + (s2 + s3));
    if (!sub) {
      float d = Db[i];
      sc[i] = d * s + 2.f * d * ydt[0][i];
    }
  }
  __syncthreads();
  {
    int i = t >> 2, sub = t & 3;
    float v = sc[i];
    int rk = 0;
    int j0 = sub * 64;
    for (int j = j0; j < j0 + 64; j++) {
      float u = sc[j];
      rk += (u > v) || (u == v && j < i);
    }
    rk = grp_isum<4>(rk);
    if (!sub && rk < 30) sord[rk] = i;
  }
  __syncthreads();
  stepB(6, 1);
  __syncthreads();
  for (int ft = 0; ft < 6; ft++) {
    stepA(ft);
    __syncthreads();
    stepB(ft, 16);
    __syncthreads();
  }
}

// ---------- fused head (4-acc split loops) ----------
__global__ __launch_bounds__(256) void k_head2(const float* __restrict__ spg,
                                               const float* __restrict__ c1W,
                                               const float* __restrict__ c1b,
                                               const float* __restrict__ c2W,
                                               const float* __restrict__ c2b,
                                               const float* __restrict__ oW,
                                               const float* __restrict__ ob,
                                               float* __restrict__ out) {
  int b = blockIdx.x, t = threadIdx.x;
  __shared__ float sp[30 * 97];
  __shared__ float y1[16 * 30];
  __shared__ float yp[16 * 15];
  __shared__ float yc[32 * 11];
  __shared__ float red[256];
  const float* spb = spg + (size_t)b * 30 * 97;
  for (int idx = t; idx < 30 * 97; idx += 256) sp[idx] = spb[idx];
  __syncthreads();
  for (int idx = t; idx < 16 * 30; idx += 256) {
    int c = idx / 30, kk = idx - c * 30;
    float a0 = 0.f, a1 = 0.f, a2 = 0.f, a3 = 0.f;
    for (int d = 0; d < 96; d += 4) {
      a0 += sp[kk * 97 + d]     * c1W[c * 97 + d];
      a1 += sp[kk * 97 + d + 1] * c1W[c * 97 + d + 1];
      a2 += sp[kk * 97 + d + 2] * c1W[c * 97 + d + 2];
      a3 += sp[kk * 97 + d + 3] * c1W[c * 97 + d + 3];
    }
    float a = c1b[c] + ((a0 + a1) + (a2 + a3)) + sp[kk * 97 + 96] * c1W[c * 97 + 96];
    y1[c * 30 + kk] = fmaxf(a, 0.f);
  }
  __syncthreads();
  for (int idx = t; idx < 16 * 15; idx += 256) {
    int c = idx / 15, t2 = idx - c * 15;
    yp[idx] = fmaxf(y1[c * 30 + 2 * t2], y1[c * 30 + 2 * t2 + 1]);
  }
  __syncthreads();
  for (int idx = t; idx < 32 * 11; idx += 256) {
    int o = idx / 11, t3 = idx - o * 11;
    float a0 = 0.f, a1 = 0.f, a2 = 0.f, a3 = 0.f;
    for (int i2 = 0; i2 < 16; i2 += 4)
      for (int ww = 0; ww < 5; ww++) {
        a0 += yp[i2 * 15 + t3 + ww]       * c2W[(o * 16 + i2) * 5 + ww];
        a1 += yp[(i2 + 1) * 15 + t3 + ww] * c2W[(o * 16 + i2 + 1) * 5 + ww];
        a2 += yp[(i2 + 2) * 15 + t3 + ww] * c2W[(o * 16 + i2 + 2) * 5 + ww];
        a3 += yp[(i2 + 3) * 15 + t3 + ww] * c2W[(o * 16 + i2 + 3) * 5 + ww];
      }
    float a = c2b[o] + ((a0 + a1) + (a2 + a3));
    yc[o * 11 + t3] = fmaxf(a, 0.f);
  }
  __syncthreads();
  {
    int o = t & 31, g = t >> 5;   // 8 groups of 44
    float a0 = 0.f, a1 = 0.f, a2 = 0.f, a3 = 0.f;
    int base = g * 44;
    for (int qq = 0; qq < 44; qq += 4) {
      a0 += yc[base + qq]     * oW[(base + qq) * 32 + o];
      a1 += yc[base + qq + 1] * oW[(base + qq + 1) * 32 + o];
      a2 += yc[base + qq + 2] * oW[(base + qq + 2) * 32 + o];
      a3 += yc[base + qq + 3] * oW[(base + qq + 3) * 32 + o];
    }
    red[t] = (a0 + a1) + (a2 + a3);
  }
  __syncthreads();
  if (t < 32) {
    float a = ob[t];
    #pragma unroll
    for (int g = 0; g < 8; g++) a += red[t + 32 * g];
    out[(size_t)b * 32 + t] = fmaxf(a, 0.f);
  }
}

extern "C" void kernel_launch(void* const* d_in, const int* in_sizes, int n_in,
                              void* d_out, int out_size, void* d_ws, size_t ws_size,
                              hipStream_t stream) {
  const float* x   = (const float*)d_in[0];
  const float* A0  = (const float*)d_in[1];
  const float* dW0 = (const float*)d_in[2];
  const float* db0 = (const float*)d_in[3];
  const float* dW  = (const float*)d_in[4];
  const float* dbv = (const float*)d_in[5];
  const float* pp  = (const float*)d_in[6];
  const float* uW  = (const float*)d_in[7];
  const float* ub  = (const float*)d_in[8];
  const float* uWl = (const float*)d_in[9];
  const float* ubl = (const float*)d_in[10];
  const float* c1W = (const float*)d_in[11];
  const float* c1b = (const float*)d_in[12];
  const float* c2W = (const float*)d_in[13];
  const float* c2b = (const float*)d_in[14];
  const float* oW  = (const float*)d_in[15];
  const float* ob  = (const float*)d_in[16];
  float* out = (float*)d_out;

  float* base = (float*)d_ws;
  size_t off = 0;
  auto alloc = [&](size_t nel) { nel = (nel + 3) & ~(size_t)3; float* p = base + off; off += nel; return p; };
  float* H0 = alloc((size_t)BATCH * 256 * HID);
  float* H1 = alloc((size_t)BATCH * 128 * HID);
  float* D0 = alloc((size_t)BATCH * 256);
  float* D1 = alloc((size_t)BATCH * 128);
  float* SP = alloc((size_t)BATCH * 30 * 97);
  unsigned short* Abf0 = (unsigned short*)alloc((size_t)BATCH * 256 * 256 / 2);
  unsigned short* Abf1 = (unsigned short*)alloc((size_t)BATCH * 128 * 128 / 2);
  unsigned short* Wp   = (unsigned short*)alloc((size_t)3 * WTOT / 2 + 4);

  // 1. prologue: A0 -> bf16 + dinv; weight planes
  k_prepA<<<BATCH * 256 / 4, 256, 0, stream>>>(A0, Abf0, D0, BATCH * 256);
  k_splitW3<<<(WTOT + 255) / 256, 256, 0, stream>>>(dW0, dW, uW, uWl, Wp);

  // 2. first GCN (n=256) fully fused, 16 waves/block
  k_big<<<BATCH, 1024, 0, stream>>>(x, Wp + WOFF_DW0, Abf0, D0, db0, H0);

  // 3. pool0 + aug1 + enc GCN@128 + inner U + dec GCN@128 + scatter -> H0
  k_mid<<<BATCH, 1024, 0, stream>>>(Abf0, Abf1, H0, H1, D1, Wp, dW, dbv, pp, uW, ub);

  // 4. fused final GCN: per-ft yd tiles in LDS + col-96 + rank + top-30 rows
  k_tail<<<BATCH, 1024, 0, stream>>>(H0, Wp + WOFF_UWL, Abf0, D0, ubl, SP);

  // 5. fused head
  k_head2<<<BATCH, 256, 0, stream>>>(SP, c1W, c1b, c2W, c2b, oW, ob, out);
}

// Round 10
// 355.683 us; speedup vs baseline: 1.0686x; 1.0529x over previous
//
#include <hip/hip_runtime.h>
#include <math.h>

#define BATCH 256
#define NNODE 256
#define FIN   128
#define HID   48
#define DOUT  97

// packed transposed weight planes (ushort elements, per-plane offsets)
#define WOFF_DW0 0        // dW0^T [48][128]
#define WOFF_DW  6144     // dW[i]^T 4 x [48][64]
#define WOFF_UW  18432    // uW[i]^T 3 x [48][64]
#define WOFF_UWL 27648    // uWl^T  [112][64]
#define WTOT     34816    // per-plane stride

typedef __attribute__((ext_vector_type(8))) short bf16x8_t;
typedef __attribute__((ext_vector_type(4))) float f32x4_t;

__device__ inline unsigned short f2bf(float x) {
  unsigned u = __float_as_uint(x);
  u += 0x7fff + ((u >> 16) & 1);
  return (unsigned short)(u >> 16);
}
__device__ inline float bf2f(unsigned short h) {
  return __uint_as_float(((unsigned)h) << 16);
}

template<int L> __device__ inline float grp_sum(float v) {
  #pragma unroll
  for (int o = L >> 1; o > 0; o >>= 1) v += __shfl_xor(v, o);
  return v;
}
template<int L> __device__ inline int grp_isum(int v) {
  #pragma unroll
  for (int o = L >> 1; o > 0; o >>= 1) v += __shfl_xor(v, o);
  return v;
}

// ---------- fused A0 pass: bf16 convert + rowsum -> dinv (exact: 0/1 entries) ----------
__global__ __launch_bounds__(256) void k_prepA(const float* __restrict__ A,
                                               unsigned short* __restrict__ Abf,
                                               float* __restrict__ dinv, int rows) {
  int wid = (blockIdx.x * 256 + threadIdx.x) >> 6;
  int lane = threadIdx.x & 63;
  if (wid >= rows) return;
  const float4* rp = (const float4*)(A + (size_t)wid * 256);
  float4 v = rp[lane];
  unsigned long long pk = (unsigned long long)f2bf(v.x)
                        | ((unsigned long long)f2bf(v.y) << 16)
                        | ((unsigned long long)f2bf(v.z) << 32)
                        | ((unsigned long long)f2bf(v.w) << 48);
  *(unsigned long long*)(Abf + (size_t)wid * 256 + lane * 4) = pk;
  float s = v.x + v.y + v.z + v.w;
  #pragma unroll
  for (int o = 32; o > 0; o >>= 1) s += __shfl_down(s, o);
  if (lane == 0) dinv[wid] = 1.0f / sqrtf(s + 2.0f);
}

// ---------- transpose + 3-plane split ALL weights (runs once, tiny) ----------
__global__ __launch_bounds__(256) void k_splitW3(const float* __restrict__ dW0,
                                                 const float* __restrict__ dW,
                                                 const float* __restrict__ uW,
                                                 const float* __restrict__ uWl,
                                                 unsigned short* __restrict__ Wp) {
  int idx = blockIdx.x * 256 + threadIdx.x;
  if (idx >= WTOT) return;
  float v;
  if (idx < WOFF_DW) {                   // dW0^T [48][128]
    int f = idx / 128, kk = idx - f * 128;
    v = dW0[kk * HID + f];
  } else if (idx < WOFF_UW) {            // dW[i]^T [48][64]
    int r = idx - WOFF_DW;
    int i = r / 3072; r -= i * 3072;
    int f = r / 64, kk = r - f * 64;
    v = (kk < HID) ? dW[((size_t)i * HID + kk) * HID + f] : 0.f;
  } else if (idx < WOFF_UWL) {           // uW[i]^T [48][64]
    int r = idx - WOFF_UW;
    int i = r / 3072; r -= i * 3072;
    int f = r / 64, kk = r - f * 64;
    v = (kk < HID) ? uW[((size_t)i * HID + kk) * HID + f] : 0.f;
  } else {                               // uWl^T [112][64]
    int r = idx - WOFF_UWL;
    int f = r / 64, kk = r - f * 64;
    v = (f < DOUT && kk < HID) ? uWl[(size_t)kk * DOUT + f] : 0.f;
  }
  unsigned short h = f2bf(v);
  float r1 = v - bf2f(h);
  unsigned short m = f2bf(r1);
  float r2 = r1 - bf2f(m);
  unsigned short l = f2bf(r2);
  Wp[idx] = h;
  Wp[idx + WTOT] = m;
  Wp[idx + 2 * WTOT] = l;
}

// ---------- wave-independent MFMA GEMM XW = X @ W, 3-plane split (final GCN only) ----------
template<int KS2>   // K-steps of 32; KP = KS2*32
__global__ __launch_bounds__(256) void k_xws(const float* __restrict__ X,
                                             const unsigned short* __restrict__ Wp,
                                             float* __restrict__ XW,
                                             const float* __restrict__ dinv,
                                             unsigned short* __restrict__ Yth,
                                             unsigned short* __restrict__ Ytl,
                                             int K, int F, int Fpad, int nShift) {
  constexpr int KP = KS2 * 32;
  int mt = (blockIdx.x * 256 + threadIdx.x) >> 6;
  int lane = threadIdx.x & 63;
  int r = lane & 15, q = lane >> 4;
  const float* xr = X + ((long)mt * 16 + r) * K;
  bf16x8_t ah[KS2], am[KS2], al[KS2];
  #pragma unroll
  for (int ks = 0; ks < KS2; ks++) {
    int col0 = ks * 32 + q * 8;
    float v[8];
    if (col0 + 8 <= K) {
      float4 a = *(const float4*)(xr + col0);
      float4 b = *(const float4*)(xr + col0 + 4);
      v[0] = a.x; v[1] = a.y; v[2] = a.z; v[3] = a.w;
      v[4] = b.x; v[5] = b.y; v[6] = b.z; v[7] = b.w;
    } else {
      #pragma unroll
      for (int j = 0; j < 8; j++) v[j] = (col0 + j < K) ? xr[col0 + j] : 0.f;
    }
    #pragma unroll
    for (int j = 0; j < 8; j++) {
      unsigned short h = f2bf(v[j]);
      float r1 = v[j] - bf2f(h);
      unsigned short m = f2bf(r1);
      float r2 = r1 - bf2f(m);
      unsigned short l = f2bf(r2);
      ah[ks][j] = (short)h;
      am[ks][j] = (short)m;
      al[ks][j] = (short)l;
    }
  }
  long row0 = (long)mt * 16 + q * 4;
  float4 dv4 = {0.f, 0.f, 0.f, 0.f};
  long ytBase = 0;
  if (Yth) {
    dv4 = *(const float4*)(dinv + row0);
    int bb = (int)(row0 >> nShift);
    int jj = (int)(row0 & ((1 << nShift) - 1));
    ytBase = (long)bb * Fpad;
    ytBase = ytBase << nShift;
    ytBase += jj;
  }
  int nFT = Fpad >> 4;
  for (int ft = 0; ft < nFT; ft++) {
    int fl = ft * 16 + r;
    const unsigned short* wb = Wp + (size_t)fl * KP + q * 8;
    f32x4_t acc = {0.f, 0.f, 0.f, 0.f};
    #pragma unroll
    for (int ks = 0; ks < KS2; ks++) {
      bf16x8_t bh = *(const bf16x8_t*)(wb + ks * 32);
      bf16x8_t bm = *(const bf16x8_t*)(wb + WTOT + ks * 32);
      bf16x8_t bl = *(const bf16x8_t*)(wb + 2 * WTOT + ks * 32);
      acc = __builtin_amdgcn_mfma_f32_16x16x32_bf16(ah[ks], bh, acc, 0, 0, 0);
      acc = __builtin_amdgcn_mfma_f32_16x16x32_bf16(ah[ks], bm, acc, 0, 0, 0);
      acc = __builtin_amdgcn_mfma_f32_16x16x32_bf16(am[ks], bh, acc, 0, 0, 0);
      acc = __builtin_amdgcn_mfma_f32_16x16x32_bf16(am[ks], bm, acc, 0, 0, 0);
      acc = __builtin_amdgcn_mfma_f32_16x16x32_bf16(ah[ks], bl, acc, 0, 0, 0);
      acc = __builtin_amdgcn_mfma_f32_16x16x32_bf16(al[ks], bh, acc, 0, 0, 0);
    }
    int f = fl;
    if (f < F) {
      if (XW) {
        #pragma unroll
        for (int reg = 0; reg < 4; reg++) XW[(row0 + reg) * F + f] = acc[reg];
      }
      if (Yth) {
        float dvv[4] = {dv4.x, dv4.y, dv4.z, dv4.w};
        unsigned long long hpk = 0, lpk = 0;
        #pragma unroll
        for (int reg = 0; reg < 4; reg++) {
          float v = dvv[reg] * acc[reg];
          unsigned short hi = f2bf(v);
          unsigned short lo = f2bf(v - bf2f(hi));
          hpk |= ((unsigned long long)hi) << (16 * reg);
          lpk |= ((unsigned long long)lo) << (16 * reg);
        }
        long o = ytBase + ((long)f << nShift);
        *(unsigned long long*)(Yth + o) = hpk;
        *(unsigned long long*)(Ytl + o) = lpk;
      }
    }
  }
}

// ---------- fused first GCN (n=256, K=128): 16 waves, 1 m-tile / it-tile per wave ----------
__global__ __launch_bounds__(1024) void k_big(const float* __restrict__ x,
                                              const unsigned short* __restrict__ Wp0,
                                              const unsigned short* __restrict__ Abf0,
                                              const float* __restrict__ D0,
                                              const float* __restrict__ db0,
                                              float* __restrict__ H0) {
  __shared__ __align__(16) char yt0[24576];   // XWdT hi [48][256] bf16, swizzled
  __shared__ __align__(16) char yt1[24576];   // XWdT lo
  int b = blockIdx.x, t = threadIdx.x;
  int w = t >> 6, lane = t & 63;
  int r = lane & 15, q = lane >> 4;
  const float* Xb = x + (size_t)b * 256 * 128;
  const float* Db = D0 + (size_t)b * 256;
  // ---- step A: XWd = D * (X @ W), 3-plane split, to LDS transposed; m = w (16 tiles) ----
  {
    int m = w;
    const float* xr = Xb + (size_t)(m * 16 + r) * 128;
    bf16x8_t ah[4], am[4], al[4];
    #pragma unroll
    for (int ks = 0; ks < 4; ks++) {
      int col0 = ks * 32 + q * 8;
      float4 a4 = *(const float4*)(xr + col0);
      float4 b4 = *(const float4*)(xr + col0 + 4);
      float v[8] = {a4.x, a4.y, a4.z, a4.w, b4.x, b4.y, b4.z, b4.w};
      #pragma unroll
      for (int j = 0; j < 8; j++) {
        unsigned short h = f2bf(v[j]); float r1 = v[j] - bf2f(h);
        unsigned short mm = f2bf(r1);  float r2 = r1 - bf2f(mm);
        ah[ks][j] = (short)h; am[ks][j] = (short)mm; al[ks][j] = (short)f2bf(r2);
      }
    }
    int row0 = m * 16 + q * 4;
    float4 dv4 = *(const float4*)(Db + row0);
    float dvv[4] = {dv4.x, dv4.y, dv4.z, dv4.w};
    #pragma unroll
    for (int ft = 0; ft < 3; ft++) {
      int fl = ft * 16 + r;
      const unsigned short* wb = Wp0 + (size_t)fl * 128 + q * 8;
      f32x4_t acc = {0.f, 0.f, 0.f, 0.f};
      #pragma unroll
      for (int ks = 0; ks < 4; ks++) {
        bf16x8_t bh = *(const bf16x8_t*)(wb + ks * 32);
        bf16x8_t bm = *(const bf16x8_t*)(wb + WTOT + ks * 32);
        bf16x8_t bl = *(const bf16x8_t*)(wb + 2 * WTOT + ks * 32);
        acc = __builtin_amdgcn_mfma_f32_16x16x32_bf16(ah[ks], bh, acc, 0, 0, 0);
        acc = __builtin_amdgcn_mfma_f32_16x16x32_bf16(ah[ks], bm, acc, 0, 0, 0);
        acc = __builtin_amdgcn_mfma_f32_16x16x32_bf16(am[ks], bh, acc, 0, 0, 0);
        acc = __builtin_amdgcn_mfma_f32_16x16x32_bf16(am[ks], bm, acc, 0, 0, 0);
        acc = __builtin_amdgcn_mfma_f32_16x16x32_bf16(ah[ks], bl, acc, 0, 0, 0);
        acc = __builtin_amdgcn_mfma_f32_16x16x32_bf16(al[ks], bh, acc, 0, 0, 0);
      }
      #pragma unroll
      for (int reg = 0; reg < 4; reg++) {
        float vv = dvv[reg] * acc[reg];
        unsigned short hi = f2bf(vv);
        unsigned short lo = f2bf(vv - bf2f(hi));
        int byte = (fl * 512 + (row0 + reg) * 2) ^ ((fl & 7) << 4);
        *(unsigned short*)(yt0 + byte) = hi;
        *(unsigned short*)(yt1 + byte) = lo;
      }
    }
  }
  __syncthreads();
  // ---- step B: H0 = relu(D A (D XW) + 2 D (D XW) + b); it = w ----
  {
    int it = w;
    const unsigned short* ap = Abf0 + ((size_t)b * 256 + it * 16 + r) * 256 + q * 8;
    bf16x8_t af[8];
    #pragma unroll
    for (int ks = 0; ks < 8; ks++) af[ks] = *(const bf16x8_t*)(ap + ks * 32);
    #pragma unroll
    for (int ft = 0; ft < 3; ft++) {
      int fl = ft * 16 + r;
      f32x4_t acc = {0.f, 0.f, 0.f, 0.f};
      #pragma unroll
      for (int ks = 0; ks < 8; ks++) {
        int byte = (fl * 512 + (ks * 32 + q * 8) * 2) ^ ((fl & 7) << 4);
        bf16x8_t bh = *(const bf16x8_t*)(yt0 + byte);
        bf16x8_t bl = *(const bf16x8_t*)(yt1 + byte);
        acc = __builtin_amdgcn_mfma_f32_16x16x32_bf16(af[ks], bh, acc, 0, 0, 0);
        acc = __builtin_amdgcn_mfma_f32_16x16x32_bf16(af[ks], bl, acc, 0, 0, 0);
      }
      float bfv = db0[fl];
      #pragma unroll
      for (int reg = 0; reg < 4; reg++) {
        int rr = it * 16 + q * 4 + reg;
        int sbyte = (fl * 512 + rr * 2) ^ ((fl & 7) << 4);
        float selfv = bf2f(*(const unsigned short*)(yt0 + sbyte))
                    + bf2f(*(const unsigned short*)(yt1 + sbyte));
        float d = Db[rr];
        float v = d * acc[reg] + 2.f * d * selfv + bfv;
        H0[((size_t)b * 256 + rr) * 48 + fl] = fmaxf(v, 0.f);
      }
    }
  }
}

// ---------- GCN@128 phase for 1024 threads: 24 (m,ft) tasks per step ----------
template<int MODE>   // 0 -> write H1; 1 -> scatter-add into H0b via sPerm1
__device__ inline void gcn128_phase(const float* __restrict__ Xg,
                                    const unsigned short* __restrict__ Wpl,
                                    const unsigned short* __restrict__ A1,
                                    const float* __restrict__ D1b,
                                    const float* __restrict__ bias,
                                    char* yt0, char* yt1,
                                    float* __restrict__ H1,
                                    float* __restrict__ H0b,
                                    const int* sPerm1, int t) {
  int w = t >> 6, lane = t & 63;
  int r = lane & 15, q = lane >> 4;
  // step A: XWdT hi/lo into LDS [48][128] swizzled; tasks (m 0..7) x (ft 0..2)
  for (int task = w; task < 24; task += 16) {
    int m = task / 3, ft = task - m * 3;
    const float* xr = Xg + (size_t)(m * 16 + r) * 48;
    bf16x8_t ah[2], am[2], al[2];
    #pragma unroll
    for (int ks = 0; ks < 2; ks++) {
      int col0 = ks * 32 + q * 8;
      float v[8];
      if (col0 + 8 <= 48) {
        float4 a4 = *(const float4*)(xr + col0);
        float4 b4 = *(const float4*)(xr + col0 + 4);
        v[0]=a4.x; v[1]=a4.y; v[2]=a4.z; v[3]=a4.w;
        v[4]=b4.x; v[5]=b4.y; v[6]=b4.z; v[7]=b4.w;
      } else {
        #pragma unroll
        for (int j = 0; j < 8; j++) v[j] = (col0 + j < 48) ? xr[col0 + j] : 0.f;
      }
      #pragma unroll
      for (int j = 0; j < 8; j++) {
        unsigned short h = f2bf(v[j]); float r1 = v[j] - bf2f(h);
        unsigned short mm = f2bf(r1);  float r2 = r1 - bf2f(mm);
        ah[ks][j] = (short)h; am[ks][j] = (short)mm; al[ks][j] = (short)f2bf(r2);
      }
    }
    int row0 = m * 16 + q * 4;
    float4 dv4 = *(const float4*)(D1b + row0);
    float dvv[4] = {dv4.x, dv4.y, dv4.z, dv4.w};
    int fl = ft * 16 + r;
    const unsigned short* wb = Wpl + (size_t)fl * 64 + q * 8;
    f32x4_t acc = {0.f, 0.f, 0.f, 0.f};
    #pragma unroll
    for (int ks = 0; ks < 2; ks++) {
      bf16x8_t bh = *(const bf16x8_t*)(wb + ks * 32);
      bf16x8_t bm = *(const bf16x8_t*)(wb + WTOT + ks * 32);
      bf16x8_t bl = *(const bf16x8_t*)(wb + 2 * WTOT + ks * 32);
      acc = __builtin_amdgcn_mfma_f32_16x16x32_bf16(ah[ks], bh, acc, 0, 0, 0);
      acc = __builtin_amdgcn_mfma_f32_16x16x32_bf16(ah[ks], bm, acc, 0, 0, 0);
      acc = __builtin_amdgcn_mfma_f32_16x16x32_bf16(am[ks], bh, acc, 0, 0, 0);
      acc = __builtin_amdgcn_mfma_f32_16x16x32_bf16(am[ks], bm, acc, 0, 0, 0);
      acc = __builtin_amdgcn_mfma_f32_16x16x32_bf16(ah[ks], bl, acc, 0, 0, 0);
      acc = __builtin_amdgcn_mfma_f32_16x16x32_bf16(al[ks], bh, acc, 0, 0, 0);
    }
    #pragma unroll
    for (int reg = 0; reg < 4; reg++) {
      float vv = dvv[reg] * acc[reg];
      unsigned short hi = f2bf(vv);
      unsigned short lo = f2bf(vv - bf2f(hi));
      int byte = (fl * 256 + (row0 + reg) * 2) ^ ((fl & 7) << 4);
      *(unsigned short*)(yt0 + byte) = hi;
      *(unsigned short*)(yt1 + byte) = lo;
    }
  }
  __syncthreads();
  // step B: tasks (it 0..7) x (ft 0..2)
  for (int task = w; task < 24; task += 16) {
    int it = task / 3, ft = task - it * 3;
    const unsigned short* ap = A1 + (size_t)(it * 16 + r) * 128 + q * 8;
    bf16x8_t af[4];
    #pragma unroll
    for (int ks = 0; ks < 4; ks++) af[ks] = *(const bf16x8_t*)(ap + ks * 32);
    int fl = ft * 16 + r;
    f32x4_t acc = {0.f, 0.f, 0.f, 0.f};
    #pragma unroll
    for (int ks = 0; ks < 4; ks++) {
      int byte = (fl * 256 + (ks * 32 + q * 8) * 2) ^ ((fl & 7) << 4);
      bf16x8_t bh = *(const bf16x8_t*)(yt0 + byte);
      bf16x8_t bl = *(const bf16x8_t*)(yt1 + byte);
      acc = __builtin_amdgcn_mfma_f32_16x16x32_bf16(af[ks], bh, acc, 0, 0, 0);
      acc = __builtin_amdgcn_mfma_f32_16x16x32_bf16(af[ks], bl, acc, 0, 0, 0);
    }
    float bfv = bias[fl];
    #pragma unroll
    for (int reg = 0; reg < 4; reg++) {
      int rr = it * 16 + q * 4 + reg;
      int sbyte = (fl * 256 + rr * 2) ^ ((fl & 7) << 4);
      float selfv = bf2f(*(const unsigned short*)(yt0 + sbyte))
                  + bf2f(*(const unsigned short*)(yt1 + sbyte));
      float d = D1b[rr];
      float v = d * acc[reg] + 2.f * d * selfv + bfv;
      v = fmaxf(v, 0.f);
      if (MODE == 0) H1[(size_t)rr * 48 + fl] = v;
      else {
        int node = sPerm1[rr];
        H0b[(size_t)node * 48 + fl] += v;
      }
    }
  }
  __syncthreads();
}

// ---------- inner-U device helpers (1024-thread) ----------
__device__ inline void xw_dphase(const float* hin, const float* W, const float* dv,
                                 float* xwd, int n, int t) {
  for (int idx = t; idx < n * 48; idx += 1024) {
    int j = idx / 48, f = idx - j * 48;
    const float* hr = hin + j * 48;
    float a = 0.f;
    #pragma unroll
    for (int g = 0; g < 48; g++) a += hr[g] * W[g * 48 + f];
    xwd[idx] = dv[j] * a;
  }
}

__device__ inline void anxw_phase(const float* A, int lda, const float* xwd,
                                  const float* dv, const float* bias,
                                  float* hout, int n, int t) {
  for (int idx = t; idx < n * 48; idx += 1024) {
    int i = idx / 48, f = idx - i * 48;
    const float* ar = A + i * lda;
    float acc = 0.f;
    #pragma unroll 4
    for (int j = 0; j < n; j++) acc += ar[j] * xwd[j * 48 + f];
    float di = dv[i];
    float v = di * acc + 2.f * di * xwd[i * 48 + f] + bias[f];
    hout[idx] = fmaxf(v, 0.f);
  }
}

template<int N, int K>
__device__ inline void pool_phaseT(const float* h, const float* p,
                                   float* sS, int* perm, float* hin, int t) {
  constexpr int LPR = 1024 / N;
  int row = t / LPR, sub = t % LPR;
  float pn = 0.f;
  #pragma unroll
  for (int g = 0; g < 48; g++) pn += p[g] * p[g];
  const float* hr = h + row * 48;
  float acc = 0.f;
  for (int g = sub; g < 48; g += LPR) acc += hr[g] * p[g];
  acc = grp_sum<LPR>(acc);
  if (sub == 0) sS[row] = tanhf(acc / sqrtf(pn));
  __syncthreads();
  {
    float v = sS[row];
    int r = 0;
    for (int j = sub; j < N; j += LPR) {
      float u = sS[j];
      r += (u > v) || (u == v && j < row);
    }
    r = grp_isum<LPR>(r);
    if (sub == 0 && r < K) perm[r] = row;
  }
  __syncthreads();
  for (int idx = t; idx < K * 48; idx += 1024) {
    int r = idx / 48, g = idx - r * 48;
    int pi = perm[r];
    hin[idx] = h[pi * 48 + g] * sS[pi];
  }
  __syncthreads();
}

template<int NN, int KK>
__device__ inline void aug_phaseT(const float* A, int lda, const int* perm,
                                  float* Ao, int ldo, float* dout, int t) {
  for (int idx = t; idx < KK * KK; idx += 1024) {
    int r = idx / KK, c = idx - r * KK;
    int pr = perm[r], pc = perm[c];
    const float* ra = A + pr * lda;
    const float* rc = A + pc * lda;
    float acc = 0.f;
    #pragma unroll 4
    for (int j = 0; j < NN; j++) acc += ra[j] * rc[j];
    float v = acc + 2.f * ra[pc];
    Ao[r * ldo + c] = (r == c) ? 0.f : v;
  }
  __syncthreads();
  {
    constexpr int LPR = 1024 / KK;
    int row = t / LPR, sub = t % LPR;
    float s = 0.f;
    for (int j = sub; j < KK; j += LPR) s += Ao[row * ldo + j];
    s = grp_sum<(LPR > 64 ? 64 : LPR)>(s);
    if (sub == 0) dout[row] = 1.0f / sqrtf(s + 2.0f);
  }
  __syncthreads();
}

__device__ inline void scat_phase(const int* perm, const float* src, float* dst,
                                  int k, int t) {
  for (int idx = t; idx < k * 48; idx += 1024) {
    int r = idx / 48, g = idx - r * 48;
    dst[perm[r] * 48 + g] += src[idx];
  }
  __syncthreads();
}

// ========== k_mid: pool0 + aug1(+D1) + enc GCN@128 + inner U + dec GCN@128 + scatter H0 ==========
// 1024 threads (16 waves) per block, 1 block/batch.
__global__ __launch_bounds__(1024) void k_mid(const unsigned short* __restrict__ Abf0,
                                              unsigned short* __restrict__ Abf1g,
                                              float* __restrict__ H0,
                                              float* __restrict__ H1g,
                                              float* __restrict__ D1g,
                                              const unsigned short* __restrict__ Wp,
                                              const float* __restrict__ dW,
                                              const float* __restrict__ dbv,
                                              const float* __restrict__ pp,
                                              const float* __restrict__ uW,
                                              const float* __restrict__ ub) {
  int b = blockIdx.x, t = threadIdx.x;
  __shared__ __align__(16) char arena[63488];
  __shared__ int sPerm1[128];
  float* H1 = H1g + (size_t)b * 128 * 48;
  float* H0b = H0 + (size_t)b * 256 * 48;
  unsigned short* A1 = Abf1g + (size_t)b * 128 * 128;
  float* D1b = D1g + (size_t)b * 128;

  // ===== P0: pool0 (256 -> 128): scores, exact rank, gather into H1 (LPR=4) =====
  {
    float* sc = (float*)arena;    // [256]
    const float* p = pp;
    float pn = 0.f;
    #pragma unroll
    for (int g = 0; g < 48; g++) pn += p[g] * p[g];
    int row = t >> 2, sub = t & 3;
    const float* hr = H0b + (size_t)row * 48;
    float a = 0.f;
    for (int g = sub; g < 48; g += 4) a += hr[g] * p[g];
    a = grp_sum<4>(a);
    if (!sub) sc[row] = tanhf(a / sqrtf(pn));
    __syncthreads();
    float vv = sc[row];
    int rk = 0;
    for (int j = sub; j < 256; j += 4) {
      float u = sc[j];
      rk += (u > vv) || (u == vv && j < row);
    }
    rk = grp_isum<4>(rk);
    if (!sub && rk < 128) sPerm1[rk] = row;
    __syncthreads();
    for (int idx = t; idx < 128 * 48; idx += 1024) {
      int rr = idx / 48, g = idx - rr * 48;
      int pi = sPerm1[rr];
      H1[idx] = H0b[(size_t)pi * 48 + g] * sc[pi];
    }
  }
  __syncthreads();

  // ===== P1: aug1 MFMA (A1 = (A0+I)^2 off-diag, exact): 2 waves per it-tile =====
  {
    int w = t >> 6, lane = t & 63;
    int r = lane & 15, q = lane >> 4;
    int it = w >> 1, fh = w & 1;
    int rowA = sPerm1[it * 16 + r];
    const unsigned short* Ab = Abf0 + (size_t)b * 256 * 256;
    const unsigned short* pa = Ab + (size_t)rowA * 256 + q * 8;
    bf16x8_t af[8];
    #pragma unroll
    for (int ks = 0; ks < 8; ks++) {
      bf16x8_t a = *(const bf16x8_t*)(pa + ks * 32);
      int da = rowA - ks * 32 - q * 8;
      #pragma unroll
      for (int e = 0; e < 8; e++) if (da == e) a[e] = (short)0x3F80;
      af[ks] = a;
    }
    for (int ft = fh * 4; ft < fh * 4 + 4; ft++) {
      int rowB = sPerm1[ft * 16 + r];
      const unsigned short* pb = Ab + (size_t)rowB * 256 + q * 8;
      f32x4_t acc = {0.f, 0.f, 0.f, 0.f};
      #pragma unroll
      for (int ks = 0; ks < 8; ks++) {
        bf16x8_t bv = *(const bf16x8_t*)(pb + ks * 32);
        int db_ = rowB - ks * 32 - q * 8;
        #pragma unroll
        for (int e = 0; e < 8; e++) if (db_ == e) bv[e] = (short)0x3F80;
        acc = __builtin_amdgcn_mfma_f32_16x16x32_bf16(af[ks], bv, acc, 0, 0, 0);
      }
      int c = ft * 16 + r;
      #pragma unroll
      for (int reg = 0; reg < 4; reg++) {
        int rr = it * 16 + q * 4 + reg;
        float v = (rr == c) ? 0.f : acc[reg];
        A1[(size_t)rr * 128 + c] = f2bf(v);
      }
    }
  }
  __syncthreads();
  // D1 rowsum from bf16 A1 (exact: entries are small integers); 8 lanes/row
  {
    int row = t >> 3, sub = t & 7;
    const unsigned* ar = (const unsigned*)(A1 + (size_t)row * 128);
    float s = 0.f;
    for (int jj = sub; jj < 64; jj += 8) {
      unsigned u = ar[jj];
      s += bf2f((unsigned short)(u & 0xffffu)) + bf2f((unsigned short)(u >> 16));
    }
    s = grp_sum<8>(s);
    if (sub == 0) D1b[row] = 1.0f / sqrtf(s + 2.0f);
  }
  __syncthreads();

  // ===== P2: encoder GCN@128 (dW[0], db[0]) -> H1 =====
  gcn128_phase<0>(H1, Wp + WOFF_DW, A1, D1b, dbv,
                  (char*)arena, (char*)arena + 12288, H1, nullptr, sPerm1, t);

  // ===== P3: inner U (enc lvl1..3 + dec j=3..2 + scatter into H1) =====
  {
    float* sS  = (float*)(arena);           // [128]
    int*   sP2 = (int*)(arena + 512);       // [64]
    int*   sP3 = (int*)(arena + 768);       // [32]
    int*   sP4 = (int*)(arena + 896);       // [16]
    float* sD2 = (float*)(arena + 960);     // [64]
    float* sD3 = (float*)(arena + 1216);    // [32]
    float* sD4 = (float*)(arena + 1344);    // [16]
    float* sA2 = (float*)(arena + 1536);    // [64][65]  -> 18176
    float* sA3 = (float*)(arena + 18176);   // [32][33]  -> 22400
    float* sH2 = (float*)(arena + 22400);   // [64][48]  -> 34688
    float* sH3 = (float*)(arena + 34688);   // [32][48]  -> 40832
    float* sXW = (float*)(arena + 40832);   // [64][48]  -> 53120
    float* hin = (float*)(arena + 53120);   // [32][48]  -> 59264
    float* sH4 = (float*)(arena + 59264);   // [16][48]  -> 62336
    float* sA4 = (float*)(arena + 62336);   // [16][17]  -> 63424

    // lvl1 pool scores + rank over H1 (n=128 -> k=64), LPR=8
    {
      const float* p = pp + 48;
      float pn = 0.f;
      #pragma unroll
      for (int g = 0; g < 48; g++) pn += p[g] * p[g];
      int row = t >> 3, sub = t & 7;
      const float* hr = H1 + (size_t)row * 48;
      float acc = 0.f;
      for (int g = sub; g < 48; g += 8) acc += hr[g] * p[g];
      acc = grp_sum<8>(acc);
      if (sub == 0) sS[row] = tanhf(acc / sqrtf(pn));
      __syncthreads();
      float v = sS[row];
      int rk = 0;
      for (int j = sub; j < 128; j += 8) {
        float u = sS[j];
        rk += (u > v) || (u == v && j < row);
      }
      rk = grp_isum<8>(rk);
      if (sub == 0 && rk < 64) sP2[rk] = row;
      __syncthreads();
    }
    // aug: A2 = (A1+I)^2 off-diag via MFMA from global A1 (exact); 1 tile/wave
    {
      int w = t >> 6, lane = t & 63;
      int r = lane & 15, q = lane >> 4;
      int it = w >> 2, ft = w & 3;
      int rowA = sP2[it * 16 + r];
      int rowB = sP2[ft * 16 + r];
      const unsigned short* pa = A1 + (size_t)rowA * 128 + q * 8;
      const unsigned short* pb = A1 + (size_t)rowB * 128 + q * 8;
      f32x4_t acc = {0.f, 0.f, 0.f, 0.f};
      #pragma unroll
      for (int k0 = 0; k0 < 128; k0 += 32) {
        bf16x8_t a  = *(const bf16x8_t*)(pa + k0);
        bf16x8_t bv = *(const bf16x8_t*)(pb + k0);
        int daA = rowA - k0 - q * 8;
        int daB = rowB - k0 - q * 8;
        #pragma unroll
        for (int e = 0; e < 8; e++) {
          if (daA == e) a[e] = (short)0x3F80;
          if (daB == e) bv[e] = (short)0x3F80;
        }
        acc = __builtin_amdgcn_mfma_f32_16x16x32_bf16(a, bv, acc, 0, 0, 0);
      }
      int c = ft * 16 + r;
      #pragma unroll
      for (int reg = 0; reg < 4; reg++) {
        int rr = it * 16 + q * 4 + reg;
        sA2[rr * 65 + c] = (rr == c) ? 0.f : acc[reg];
      }
    }
    __syncthreads();
    // D2 rowsum (LPR=16)
    {
      int row = t >> 4, sub = t & 15;
      float s = 0.f;
      for (int j = sub; j < 64; j += 16) s += sA2[row * 65 + j];
      s = grp_sum<16>(s);
      if (sub == 0) sD2[row] = 1.0f / sqrtf(s + 2.0f);
    }
    __syncthreads();
    // lvl1 XWd: gather-fold from H1 global
    for (int idx = t; idx < 64 * 48; idx += 1024) {
      int j = idx / 48, f = idx - j * 48;
      int pi = sP2[j];
      const float* hr = H1 + (size_t)pi * 48;
      const float* W = dW + 2304;
      float a = 0.f;
      #pragma unroll
      for (int g = 0; g < 48; g++) a += hr[g] * W[g * 48 + f];
      sXW[idx] = sD2[j] * sS[pi] * a;
    }
    __syncthreads();
    anxw_phase(sA2, 65, sXW, sD2, dbv + 48, sH2, 64, t);
    __syncthreads();

    // lvl2 (64 -> 32)
    pool_phaseT<64, 32>(sH2, pp + 96, sS, sP3, hin, t);
    aug_phaseT<64, 32>(sA2, 65, sP3, sA3, 33, sD3, t);
    xw_dphase(hin, dW + 2 * 2304, sD3, sXW, 32, t);
    __syncthreads();
    anxw_phase(sA3, 33, sXW, sD3, dbv + 96, sH3, 32, t);
    __syncthreads();

    // lvl3 (32 -> 16)
    pool_phaseT<32, 16>(sH3, pp + 144, sS, sP4, hin, t);
    aug_phaseT<32, 16>(sA3, 33, sP4, sA4, 17, sD4, t);
    xw_dphase(hin, dW + 3 * 2304, sD4, sXW, 16, t);
    __syncthreads();
    anxw_phase(sA4, 17, sXW, sD4, dbv + 144, sH4, 16, t);
    __syncthreads();

    // dec j=3
    scat_phase(sP4, sH4, sH3, 16, t);
    xw_dphase(sH3, uW, sD3, sXW, 32, t);
    __syncthreads();
    anxw_phase(sA3, 33, sXW, sD3, ub, sH3, 32, t);
    __syncthreads();

    // dec j=2
    scat_phase(sP3, sH3, sH2, 32, t);
    xw_dphase(sH2, uW + 2304, sD2, sXW, 64, t);
    __syncthreads();
    anxw_phase(sA2, 65, sXW, sD2, ub + 48, sH2, 64, t);
    __syncthreads();

    // H1 += up(sH2)
    for (int idx = t; idx < 64 * 48; idx += 1024) {
      int r2 = idx / 48, g = idx - r2 * 48;
      H1[(size_t)sP2[r2] * 48 + g] += sH2[idx];
    }
  }
  __syncthreads();

  // ===== P4: decoder GCN@128 (uW[2], ub[2]) -> scatter-add into H0 =====
  gcn128_phase<1>(H1, Wp + WOFF_UW + 2 * 3072, A1, D1b, ub + 96,
                  (char*)arena, (char*)arena + 12288, nullptr, H0b, sPerm1, t);
}

// ---------- fused final-GCN tail: col-96 scores + top-30 rank + top-30 rows (MFMA) ----------
__global__ __launch_bounds__(1024) void k_htail(const unsigned short* __restrict__ Abf,
                                                const float* __restrict__ dinv,
                                                const unsigned short* __restrict__ Yth,
                                                const unsigned short* __restrict__ Ytl,
                                                const float* __restrict__ ubl,
                                                float* __restrict__ sp) {
  int b = blockIdx.x, t = threadIdx.x;
  __shared__ float sy[256];
  __shared__ float sc[256];
  __shared__ int sord[32];
  const unsigned short* yh = Yth + ((size_t)b * 112 + 96) * 256;
  const unsigned short* yl = Ytl + ((size_t)b * 112 + 96) * 256;
  if (t < 256) sy[t] = bf2f(yh[t]) + bf2f(yl[t]);
  __syncthreads();
  // col scores: 4 lanes per node
  {
    int i = t >> 2, sub = t & 3;
    const unsigned short* ar = Abf + ((size_t)b * 256 + i) * 256 + sub * 64;
    const float* syp = sy + sub * 64;
    float s = 0.f;
    for (int j = 0; j < 64; j += 2) {
      unsigned u = *(const unsigned*)(ar + j);
      s += bf2f((unsigned short)(u & 0xffffu)) * syp[j]
         + bf2f((unsigned short)(u >> 16)) * syp[j + 1];
    }
    s = grp_sum<4>(s);
    if (sub == 0) {
      float d = dinv[(size_t)b * 256 + i];
      sc[i] = d * s + 2.f * d * sy[i];
    }
  }
  __syncthreads();
  // exact top-30 rank: 4 lanes per node
  {
    int i = t >> 2, sub = t & 3;
    float v = sc[i];
    int rk = 0;
    int j0 = sub * 64;
    for (int j = j0; j < j0 + 64; j++) {
      float u = sc[j];
      rk += (u > v) || (u == v && j < i);
    }
    rk = grp_isum<4>(rk);
    if (sub == 0 && rk < 30) sord[rk] = i;
  }
  __syncthreads();
  // top-30 rows via gathered-A MFMA: 14 tasks (it 0..1) x (ft 0..6), 1 per wave
  int w = t >> 6, lane = t & 63;
  if (w < 14) {
    int it = w / 7, ft = w % 7;
    int r = lane & 15, q = lane >> 4;
    int ari = it * 16 + r;
    int arow = sord[ari < 30 ? ari : 0];
    const unsigned short* ap = Abf + ((size_t)b * 256 + arow) * 256 + q * 8;
    bf16x8_t af[8];
    #pragma unroll
    for (int ks = 0; ks < 8; ks++) af[ks] = *(const bf16x8_t*)(ap + ks * 32);
    int fl = ft * 16 + r;
    const unsigned short* yrowh = Yth + ((size_t)b * 112 + fl) * 256;
    const unsigned short* yrowl = Ytl + ((size_t)b * 112 + fl) * 256;
    f32x4_t acc = {0.f, 0.f, 0.f, 0.f};
    #pragma unroll
    for (int ks = 0; ks < 8; ks++) {
      bf16x8_t bh = *(const bf16x8_t*)(yrowh + q * 8 + ks * 32);
      bf16x8_t bl = *(const bf16x8_t*)(yrowl + q * 8 + ks * 32);
      acc = __builtin_amdgcn_mfma_f32_16x16x32_bf16(af[ks], bh, acc, 0, 0, 0);
      acc = __builtin_amdgcn_mfma_f32_16x16x32_bf16(af[ks], bl, acc, 0, 0, 0);
    }
    if (fl < DOUT) {
      float bf = ubl[fl];
      #pragma unroll
      for (int reg = 0; reg < 4; reg++) {
        int rowidx = it * 16 + q * 4 + reg;
        if (rowidx < 30) {
          int node = sord[rowidx];
          float d = dinv[(size_t)b * 256 + node];
          float yv = bf2f(yrowh[node]) + bf2f(yrowl[node]);
          sp[((size_t)b * 30 + rowidx) * DOUT + fl] = d * acc[reg] + 2.f * d * yv + bf;
        }
      }
    }
  }
}

// ---------- fused head (reads precomputed sp[b][30][97]) ----------
__global__ __launch_bounds__(256) void k_head2(const float* __restrict__ spg,
                                               const float* __restrict__ c1W,
                                               const float* __restrict__ c1b,
                                               const float* __restrict__ c2W,
                                               const float* __restrict__ c2b,
                                               const float* __restrict__ oW,
                                               const float* __restrict__ ob,
                                               float* __restrict__ out) {
  int b = blockIdx.x, t = threadIdx.x;
  __shared__ float sp[30 * 97];
  __shared__ float y1[16 * 30];
  __shared__ float yp[16 * 15];
  __shared__ float yc[32 * 11];
  __shared__ float red[256];
  const float* spb = spg + (size_t)b * 30 * 97;
  for (int idx = t; idx < 30 * 97; idx += 256) sp[idx] = spb[idx];
  __syncthreads();
  for (int idx = t; idx < 16 * 30; idx += 256) {
    int c = idx / 30, kk = idx - c * 30;
    float a = c1b[c];
    for (int d = 0; d < 97; d++) a += sp[kk * 97 + d] * c1W[c * 97 + d];
    y1[c * 30 + kk] = fmaxf(a, 0.f);
  }
  __syncthreads();
  for (int idx = t; idx < 16 * 15; idx += 256) {
    int c = idx / 15, t2 = idx - c * 15;
    yp[idx] = fmaxf(y1[c * 30 + 2 * t2], y1[c * 30 + 2 * t2 + 1]);
  }
  __syncthreads();
  for (int idx = t; idx < 32 * 11; idx += 256) {
    int o = idx / 11, t3 = idx - o * 11;
    float a = c2b[o];
    for (int i2 = 0; i2 < 16; i2++)
      for (int w = 0; w < 5; w++)
        a += yp[i2 * 15 + t3 + w] * c2W[(o * 16 + i2) * 5 + w];
    yc[o * 11 + t3] = fmaxf(a, 0.f);
  }
  __syncthreads();
  {
    int o = t & 31, g = t >> 5;
    float a = 0.f;
    for (int qq = g * 44; qq < g * 44 + 44; qq++) a += yc[qq] * oW[qq * 32 + o];
    red[t] = a;
  }
  __syncthreads();
  if (t < 32) {
    float a = ob[t];
    #pragma unroll
    for (int g = 0; g < 8; g++) a += red[t + 32 * g];
    out[(size_t)b * 32 + t] = fmaxf(a, 0.f);
  }
}

extern "C" void kernel_launch(void* const* d_in, const int* in_sizes, int n_in,
                              void* d_out, int out_size, void* d_ws, size_t ws_size,
                              hipStream_t stream) {
  const float* x   = (const float*)d_in[0];
  const float* A0  = (const float*)d_in[1];
  const float* dW0 = (const float*)d_in[2];
  const float* db0 = (const float*)d_in[3];
  const float* dW  = (const float*)d_in[4];
  const float* dbv = (const float*)d_in[5];
  const float* pp  = (const float*)d_in[6];
  const float* uW  = (const float*)d_in[7];
  const float* ub  = (const float*)d_in[8];
  const float* uWl = (const float*)d_in[9];
  const float* ubl = (const float*)d_in[10];
  const float* c1W = (const float*)d_in[11];
  const float* c1b = (const float*)d_in[12];
  const float* c2W = (const float*)d_in[13];
  const float* c2b = (const float*)d_in[14];
  const float* oW  = (const float*)d_in[15];
  const float* ob  = (const float*)d_in[16];
  float* out = (float*)d_out;

  float* base = (float*)d_ws;
  size_t off = 0;
  auto alloc = [&](size_t nel) { nel = (nel + 3) & ~(size_t)3; float* p = base + off; off += nel; return p; };
  float* H0 = alloc((size_t)BATCH * 256 * HID);
  float* H1 = alloc((size_t)BATCH * 128 * HID);
  float* D0 = alloc((size_t)BATCH * 256);
  float* D1 = alloc((size_t)BATCH * 128);
  float* SP = alloc((size_t)BATCH * 30 * 97);
  unsigned short* Abf0 = (unsigned short*)alloc((size_t)BATCH * 256 * 256 / 2);
  unsigned short* Abf1 = (unsigned short*)alloc((size_t)BATCH * 128 * 128 / 2);
  unsigned short* Yth  = (unsigned short*)alloc((size_t)BATCH * 112 * 256 / 2);
  unsigned short* Ytl  = (unsigned short*)alloc((size_t)BATCH * 112 * 256 / 2);
  unsigned short* Wp   = (unsigned short*)alloc((size_t)3 * WTOT / 2 + 4);

  // 1. prologue: A0 -> bf16 + dinv; weight planes
  k_prepA<<<BATCH * 256 / 4, 256, 0, stream>>>(A0, Abf0, D0, BATCH * 256);
  k_splitW3<<<(WTOT + 255) / 256, 256, 0, stream>>>(dW0, dW, uW, uWl, Wp);

  // 2. first GCN (n=256) fully fused, 16 waves/block
  k_big<<<BATCH, 1024, 0, stream>>>(x, Wp + WOFF_DW0, Abf0, D0, db0, H0);

  // 3. pool0 + aug1 + enc GCN@128 + inner U + dec GCN@128 + scatter -> H0, 16 waves/block
  k_mid<<<BATCH, 1024, 0, stream>>>(Abf0, Abf1, H0, H1, D1, Wp, dW, dbv, pp, uW, ub);

  // 4. final GCN (uWl): XW -> Yt, then fused col-96 + rank + top-30 rows
  k_xws<2><<<BATCH * 256 / 64, 256, 0, stream>>>(H0, Wp + WOFF_UWL, nullptr,
                                                 D0, Yth, Ytl, HID, DOUT, 112, 8);
  k_htail<<<BATCH, 1024, 0, stream>>>(Abf0, D0, Yth, Ytl, ubl, SP);

  // 5. fused head
  k_head2<<<BATCH, 256, 0, stream>>>(SP, c1W, c1b, c2W, c2b, oW, ob, out);
}